// Round 1
// 2639.158 us; speedup vs baseline: 1.8092x; 1.8092x over previous
//
#include <hip/hip_runtime.h>
#include <math.h>

// ---------------------------------------------------------------------------
// Problem constants
// ---------------------------------------------------------------------------
#define BATCH 4
#define S_V 768
#define S_E 64
#define SEQ 832
#define W_V 2048
#define W_E 1024
#define NH 8
#define DH 256
#define MLP_V 16384
#define MLP_E 4096
#define EPS 1e-6f
#define ATT_SCALE 0.0625f
#define LOG2E 1.4426950408889634f

typedef __attribute__((ext_vector_type(8))) __bf16 bf16x8;
typedef __attribute__((ext_vector_type(4))) float f32x4;

__device__ __forceinline__ short f2bf(float f) {
    union { float f; unsigned u; } v; v.f = f;
    unsigned r = v.u + 0x7FFFu + ((v.u >> 16) & 1u);
    return (short)(r >> 16);
}
__device__ __forceinline__ float bf2f(short s) {
    union { unsigned u; float f; } v;
    v.u = ((unsigned)(unsigned short)s) << 16;
    return v.f;
}

// global -> LDS direct DMA, 16B per lane (m97 pattern).
#define G2L(gp, lp)                                                          \
    __builtin_amdgcn_global_load_lds(                                        \
        (const __attribute__((address_space(1))) unsigned int*)              \
            (unsigned long long)(const void*)(gp),                           \
        (__attribute__((address_space(3))) unsigned int*)                    \
            (unsigned int)(unsigned long long)(const void*)(lp),             \
        16, 0, 0)

// ---------------------------------------------------------------------------
// bf16 MFMA GEMM, m97 structure: 128x128 tile, BK=32, 4 waves, 16x16x32 MFMA.
//   A: bf16, row m at A + (m/rpb)*a_bs + (m%rpb)*K
//   Bt: bf16 [N][K] row-major (pre-transposed weight)
//   C/Cb: row m at base + (m/rpb)*c_bs + (m%rpb)*N
//   flags: 1=+res, 2=*gate[b*3072+gate_off+n], 4=+=C (f32 accum), 8=write bf16
// ---------------------------------------------------------------------------
__global__ __launch_bounds__(256) void bgemm_k(
    const short* __restrict__ A, const short* __restrict__ Bt,
    float* __restrict__ C, short* __restrict__ Cb,
    const float* __restrict__ res, const float* __restrict__ gate, int gate_off,
    int N, int K, int rpb,
    long long a_bs, long long c_bs, long long r_bs, int flags)
{
    __shared__ short Asd[4096];   // [128][32] bf16 row-major, 64B rows
    __shared__ short Bsd[4096];   // [128][32]

    const int t  = threadIdx.x;
    const int bm = blockIdx.y * 128;
    const int bn = blockIdx.x * 128;

    const short* gA[2];
    const short* gB[2];
    int lof[2];
#pragma unroll
    for (int l = 0; l < 2; l++) {
        int off = l * 4096 + t * 16;       // byte offset within 8KB tile
        int row = off >> 6;                // 64B per LDS row
        int kel = (off & 63) >> 1;         // bf16 element offset within k-tile
        lof[l] = off;
        int m = bm + row;
        gA[l] = A + (long long)(m / rpb) * a_bs + (long long)(m % rpb) * K + kel;
        gB[l] = Bt + (long long)(bn + row) * K + kel;
    }

    const int lane = t & 63;
    const int w    = t >> 6;
    const int wm   = (w >> 1) * 64;
    const int wn   = (w & 1) * 64;
    const int lr   = lane & 15;
    const int quad = lane >> 4;

    f32x4 acc[4][4];
#pragma unroll
    for (int i = 0; i < 4; i++)
#pragma unroll
        for (int j = 0; j < 4; j++) acc[i][j] = (f32x4){0.f, 0.f, 0.f, 0.f};

    for (int k0 = 0; k0 < K; k0 += 32) {
        __syncthreads();
#pragma unroll
        for (int l = 0; l < 2; l++) {
            G2L(gA[l] + k0, (char*)Asd + lof[l]);
            G2L(gB[l] + k0, (char*)Bsd + lof[l]);
        }
        __syncthreads();

        bf16x8 af[4], bfr[4];
#pragma unroll
        for (int i = 0; i < 4; i++)
            af[i] = *(const bf16x8*)&Asd[(wm + i * 16 + lr) * 32 + quad * 8];
#pragma unroll
        for (int j = 0; j < 4; j++)
            bfr[j] = *(const bf16x8*)&Bsd[(wn + j * 16 + lr) * 32 + quad * 8];
#pragma unroll
        for (int i = 0; i < 4; i++)
#pragma unroll
            for (int j = 0; j < 4; j++)
                acc[i][j] = __builtin_amdgcn_mfma_f32_16x16x32_bf16(
                    af[i], bfr[j], acc[i][j], 0, 0, 0);
    }

#pragma unroll
    for (int i = 0; i < 4; i++) {
#pragma unroll
        for (int r = 0; r < 4; r++) {
            int m = bm + wm + i * 16 + quad * 4 + r;
            long long bb = m / rpb;
            long long ss = m % rpb;
            long long rowb = bb * c_bs + ss * (long long)N;
            const float* rp = (flags & 1) ? res + bb * r_bs + ss * (long long)N : nullptr;
            const float* gp = (flags & 2) ? gate + bb * 3072 + gate_off : nullptr;
#pragma unroll
            for (int j = 0; j < 4; j++) {
                int n = bn + wn + j * 16 + lr;
                float v = acc[i][j][r];
                if (flags & 2) v *= gp[n];
                if (flags & 4) v += C[rowb + n];
                if (flags & 1) v += rp[n];
                if (flags & 8) Cb[rowb + n] = f2bf(v);
                else           C[rowb + n] = v;
            }
        }
    }
}

// ---------------------------------------------------------------------------
// Transpose + f32->bf16: W[K][N] f32  ->  Wt[N][K] bf16.  Grid (N/64, K/64).
// ---------------------------------------------------------------------------
__global__ __launch_bounds__(256) void tcvt_k(
    const float* __restrict__ W, short* __restrict__ Wt, int K, int N)
{
    __shared__ float tile[64][65];
    const int bx = blockIdx.x;   // N / 64
    const int by = blockIdx.y;   // K / 64
    const int t = threadIdx.x;
#pragma unroll
    for (int p = 0; p < 4; p++) {
        int idx = p * 256 + t;
        int r = idx >> 4;
        int c4 = (idx & 15) << 2;
        float4 v = *(const float4*)&W[(long long)(by * 64 + r) * N + bx * 64 + c4];
        tile[r][c4] = v.x; tile[r][c4 + 1] = v.y;
        tile[r][c4 + 2] = v.z; tile[r][c4 + 3] = v.w;
    }
    __syncthreads();
#pragma unroll
    for (int p = 0; p < 8; p++) {
        int idx = p * 256 + t;
        int n  = idx >> 5;
        int kp = idx & 31;
        unsigned lo = (unsigned)(unsigned short)f2bf(tile[kp * 2][n]);
        unsigned hi = (unsigned)(unsigned short)f2bf(tile[kp * 2 + 1][n]);
        *(unsigned*)&Wt[(long long)(bx * 64 + n) * K + by * 64 + kp * 2] =
            lo | (hi << 16);
    }
}

// ---------------------------------------------------------------------------
// RMSNorm * (1+w) -> bf16
// ---------------------------------------------------------------------------
__global__ __launch_bounds__(256) void rms_scale_bf(
    const float* __restrict__ x, const float* __restrict__ w,
    short* __restrict__ out, int C)
{
    const int row = blockIdx.x;
    const int t = threadIdx.x;
    const float* xp = x + (long long)row * C;
    short* op = out + (long long)row * C;
    float ss = 0.f;
    for (int i = t; i < C; i += 256) { float v = xp[i]; ss += v * v; }
    __shared__ float sred[256];
    sred[t] = ss;
    __syncthreads();
    for (int off = 128; off > 0; off >>= 1) {
        if (t < off) sred[t] += sred[t + off];
        __syncthreads();
    }
    float scale = rsqrtf(sred[0] / (float)C + EPS);
    for (int i = t; i < C; i += 256) op[i] = f2bf(xp[i] * scale * (1.f + w[i]));
}

// adaLN RMSNorm -> bf16 : rms(x)*(1+mod[b,i]) + mod[b,C+i]
__global__ __launch_bounds__(256) void rms_mod_bf(
    const float* __restrict__ x, const float* __restrict__ mod,
    short* __restrict__ out, int C, int rows_per_b)
{
    const int row = blockIdx.x;
    const int t = threadIdx.x;
    const int b = row / rows_per_b;
    const float* xp = x + (long long)row * C;
    const float* mp = mod + (long long)b * 3072;
    short* op = out + (long long)row * C;
    float ss = 0.f;
    for (int i = t; i < C; i += 256) { float v = xp[i]; ss += v * v; }
    __shared__ float sred[256];
    sred[t] = ss;
    __syncthreads();
    for (int off = 128; off > 0; off >>= 1) {
        if (t < off) sred[t] += sred[t + off];
        __syncthreads();
    }
    float scale = rsqrtf(sred[0] / (float)C + EPS);
    for (int i = t; i < C; i += 256)
        op[i] = f2bf(xp[i] * scale * (1.f + mp[i]) + mp[C + i]);
}

// ---------------------------------------------------------------------------
// Modulation: mod[b,n] = cond[b,:] @ dw[:,n] + db[n]
// ---------------------------------------------------------------------------
__global__ __launch_bounds__(256) void modln_k(
    const float* __restrict__ cond, const float* __restrict__ dw,
    const float* __restrict__ db, float* __restrict__ out)
{
    const int b = blockIdx.y;
    const int n = blockIdx.x * 256 + threadIdx.x;
    __shared__ float cs[1024];
    for (int i = threadIdx.x; i < 1024; i += 256) cs[i] = cond[b * 1024 + i];
    __syncthreads();
    float acc = db[n];
    for (int k = 0; k < 1024; k++) acc += cs[k] * dw[(long long)k * 3072 + n];
    out[b * 3072 + n] = acc;
}

// ---------------------------------------------------------------------------
// RoPE f32 -> bf16 (scaled). x[B*SEQ, heads, DH] f32; out same layout bf16.
// Grid (B*SEQ, heads), block 128.  scale folds ATT_SCALE*log2(e) into Q.
// ---------------------------------------------------------------------------
__global__ __launch_bounds__(128) void rope_bf_k(
    const float* __restrict__ x, short* __restrict__ out,
    const int* __restrict__ pos_ids, int heads, float scale)
{
    const int bs = blockIdx.x;
    const int h = blockIdx.y;
    const int d = threadIdx.x;
    const float p = (float)pos_ids[bs];
    const float inv = powf(10000.f, -(float)d / 128.f);
    const float fr = p * inv;
    const float c = cosf(fr), sn = sinf(fr);
    const float* xp = x + ((long long)bs * heads + h) * DH;
    short* op = out + ((long long)bs * heads + h) * DH;
    float x1 = xp[d];
    float x2 = xp[d + 128];
    op[d]       = f2bf((x1 * c - x2 * sn) * scale);
    op[d + 128] = f2bf((x2 * c + x1 * sn) * scale);
}

// ---------------------------------------------------------------------------
// V transpose: V[B][SEQ][DH] bf16 -> Vt[B][DH][SEQ] bf16. Grid (13, 4, B).
// ---------------------------------------------------------------------------
__global__ __launch_bounds__(256) void vt_k(
    const short* __restrict__ V, short* __restrict__ Vt)
{
    __shared__ short tile[64][72];
    const int s0 = blockIdx.x * 64;
    const int d0 = blockIdx.y * 64;
    const int b  = blockIdx.z;
    const int t = threadIdx.x;
#pragma unroll
    for (int i = 0; i < 2; i++) {
        int lin = i * 256 + t;          // 0..511
        int r = lin >> 3;               // s row 0..63
        int c8 = (lin & 7) * 8;         // d col 0..56
        *(uint4*)&tile[r][c8] =
            *(const uint4*)&V[((long long)(b * SEQ + s0 + r) << 8) + d0 + c8];
    }
    __syncthreads();
#pragma unroll
    for (int i = 0; i < 8; i++) {
        int lin = i * 256 + t;          // 0..2047
        int dr = lin >> 5;              // d row 0..63
        int sp = (lin & 31) * 2;        // s pair
        unsigned lo = (unsigned)(unsigned short)tile[sp][dr];
        unsigned hi = (unsigned)(unsigned short)tile[sp + 1][dr];
        *(unsigned*)&Vt[(long long)(b * 256 + d0 + dr) * SEQ + s0 + sp] =
            lo | (hi << 16);
    }
}

// ---------------------------------------------------------------------------
// MFMA flash attention.
//  Qb [B][S][H][D] bf16 (pre-scaled by ATT_SCALE*LOG2E), Kb [B][S][D] bf16,
//  Vt [B][D][S] bf16, out [B][S][H][D] bf16.
//  Grid (13, NH, B), block 256 = 4 waves; wave w owns rows bx*64+w*16..+15.
//  Mask structure: row-tiles 0..11 (VLM) attend keys 0..767 unmasked;
//  row-tile 12 (expert) attends 0..831 with causal compare only in k-tile 12.
//  No __syncthreads: waves are fully independent (own LDS P-slice).
// ---------------------------------------------------------------------------
__global__ __launch_bounds__(256) void attn_mfma_k(
    const short* __restrict__ Qb, const short* __restrict__ Kb,
    const short* __restrict__ Vt, short* __restrict__ out)
{
    __shared__ short Pl[4][16][72];   // per-wave P tile [row][key], padded
    const int bx = blockIdx.x;
    const int h  = blockIdx.y;
    const int b  = blockIdx.z;
    const int t  = threadIdx.x;
    const int w    = t >> 6;
    const int lane = t & 63;
    const int lr   = lane & 15;
    const int q4   = lane >> 4;

    const int r0 = bx * 64 + w * 16;           // wave's global row base
    const int nt = (bx == 12) ? 13 : 12;       // k-tiles of 64 keys

    // Q fragments: row = lr, k = q4*8 within each 32-wide k-step
    bf16x8 qf[8];
    const short* qrow = Qb + (((long long)(b * SEQ + r0 + lr) * NH + h) << 8) + q4 * 8;
#pragma unroll
    for (int ks = 0; ks < 8; ks++)
        qf[ks] = *(const bf16x8*)(qrow + ks * 32);

    f32x4 acc_o[16];
#pragma unroll
    for (int n = 0; n < 16; n++) acc_o[n] = (f32x4){0.f, 0.f, 0.f, 0.f};
    float m_run[4], l_run[4];
#pragma unroll
    for (int r = 0; r < 4; r++) { m_run[r] = -1e30f; l_run[r] = 0.f; }

    for (int kt = 0; kt < nt; kt++) {
        const int k0 = kt * 64;
        // ---- QK^T: scores in log2 domain (scale folded into Q) ----
        f32x4 s[4];
#pragma unroll
        for (int n = 0; n < 4; n++) {
            s[n] = (f32x4){0.f, 0.f, 0.f, 0.f};
            const short* krow =
                Kb + ((long long)(b * SEQ + k0 + n * 16 + lr) << 8) + q4 * 8;
#pragma unroll
            for (int ks = 0; ks < 8; ks++) {
                bf16x8 kf = *(const bf16x8*)(krow + ks * 32);
                s[n] = __builtin_amdgcn_mfma_f32_16x16x32_bf16(qf[ks], kf, s[n], 0, 0, 0);
            }
        }
        // ---- causal mask: only expert block's last k-tile ----
        if (bx == 12 && kt == 12) {
#pragma unroll
            for (int n = 0; n < 4; n++) {
                int kg = k0 + n * 16 + lr;
#pragma unroll
                for (int r = 0; r < 4; r++) {
                    int rg = r0 + q4 * 4 + r;
                    if (kg > rg) s[n][r] = -1e30f;
                }
            }
        }
        // ---- tile row-max (reduce 4 n-tiles, then 16 key-lanes) ----
        float mt[4];
#pragma unroll
        for (int r = 0; r < 4; r++)
            mt[r] = fmaxf(fmaxf(s[0][r], s[1][r]), fmaxf(s[2][r], s[3][r]));
#pragma unroll
        for (int off = 8; off >= 1; off >>= 1)
#pragma unroll
            for (int r = 0; r < 4; r++)
                mt[r] = fmaxf(mt[r], __shfl_xor(mt[r], off));
        // ---- online rescale, only when a max grows (wave-uniform) ----
        bool grow = (mt[0] > m_run[0]) | (mt[1] > m_run[1]) |
                    (mt[2] > m_run[2]) | (mt[3] > m_run[3]);
        if (__ballot(grow)) {
            float sf[4];
#pragma unroll
            for (int r = 0; r < 4; r++) {
                float mn = fmaxf(m_run[r], mt[r]);
                sf[r] = exp2f(m_run[r] - mn);
                m_run[r] = mn;
                l_run[r] *= sf[r];
            }
#pragma unroll
            for (int n = 0; n < 16; n++)
#pragma unroll
                for (int r = 0; r < 4; r++) acc_o[n][r] *= sf[r];
        }
        // ---- exp2, row-sum, P -> LDS (C-layout -> A-frag layout) ----
        float ts[4] = {0.f, 0.f, 0.f, 0.f};
#pragma unroll
        for (int n = 0; n < 4; n++) {
#pragma unroll
            for (int r = 0; r < 4; r++) {
                float p = exp2f(s[n][r] - m_run[r]);
                ts[r] += p;
                Pl[w][q4 * 4 + r][n * 16 + lr] = f2bf(p);
            }
        }
#pragma unroll
        for (int off = 8; off >= 1; off >>= 1)
#pragma unroll
            for (int r = 0; r < 4; r++) ts[r] += __shfl_xor(ts[r], off);
#pragma unroll
        for (int r = 0; r < 4; r++) l_run[r] += ts[r];
        // ---- PV: A = P from LDS, B = Vt rows (contiguous keys) ----
        bf16x8 pa[2];
#pragma unroll
        for (int ss2 = 0; ss2 < 2; ss2++)
            pa[ss2] = *(const bf16x8*)&Pl[w][lr][ss2 * 32 + q4 * 8];
        const short* vbase = Vt + ((long long)b * 256 + lr) * SEQ + k0 + q4 * 8;
#pragma unroll
        for (int n = 0; n < 16; n++) {
            const short* vrow = vbase + (long long)n * 16 * SEQ;
            bf16x8 vf0 = *(const bf16x8*)(vrow);
            bf16x8 vf1 = *(const bf16x8*)(vrow + 32);
            acc_o[n] = __builtin_amdgcn_mfma_f32_16x16x32_bf16(pa[0], vf0, acc_o[n], 0, 0, 0);
            acc_o[n] = __builtin_amdgcn_mfma_f32_16x16x32_bf16(pa[1], vf1, acc_o[n], 0, 0, 0);
        }
    }
    // ---- epilogue: O / l, bf16 store ----
    float rinv[4];
#pragma unroll
    for (int r = 0; r < 4; r++) rinv[r] = 1.f / l_run[r];
#pragma unroll
    for (int n = 0; n < 16; n++) {
#pragma unroll
        for (int r = 0; r < 4; r++) {
            int srow = r0 + q4 * 4 + r;
            out[(((long long)(b * SEQ + srow) * NH + h) << 8) + n * 16 + lr] =
                f2bf(acc_o[n][r] * rinv[r]);
        }
    }
}

// ---------------------------------------------------------------------------
// g = gelu_tanh(g) * u  (bf16, 4 elements per thread)
// ---------------------------------------------------------------------------
__global__ __launch_bounds__(256) void gelu_mul_bf(
    short* __restrict__ g, const short* __restrict__ u, long long n4)
{
    long long i = (long long)blockIdx.x * 256 + threadIdx.x;
    if (i >= n4) return;
    uint2 gv = ((const uint2*)g)[i];
    uint2 uv = ((const uint2*)u)[i];
    unsigned w[2] = {gv.x, gv.y};
    unsigned ww[2] = {uv.x, uv.y};
    unsigned o[2];
#pragma unroll
    for (int p = 0; p < 2; p++) {
        unsigned res = 0;
#pragma unroll
        for (int h = 0; h < 2; h++) {
            float x = bf2f((short)((w[p] >> (16 * h)) & 0xFFFF));
            float uu = bf2f((short)((ww[p] >> (16 * h)) & 0xFFFF));
            float th = tanhf(0.7978845608028654f * (x + 0.044715f * x * x * x));
            float r = 0.5f * x * (1.f + th) * uu;
            res |= ((unsigned)(unsigned short)f2bf(r)) << (16 * h);
        }
        o[p] = res;
    }
    ((uint2*)g)[i] = make_uint2(o[0], o[1]);
}

// ---------------------------------------------------------------------------
// kernel_launch
// ---------------------------------------------------------------------------
extern "C" void kernel_launch(void* const* d_in, const int* in_sizes, int n_in,
                              void* d_out, int out_size, void* d_ws, size_t ws_size,
                              hipStream_t stream)
{
    const float* embeds_vlm = (const float*)d_in[0];
    const float* embeds_exp = (const float*)d_in[1];
    const float* cond       = (const float*)d_in[2];
    const float* vlm_ln1_w  = (const float*)d_in[3];
    const float* vlm_ln2_w  = (const float*)d_in[4];
    const float* vlm_q_w    = (const float*)d_in[5];
    const float* vlm_k_w    = (const float*)d_in[6];
    const float* vlm_v_w    = (const float*)d_in[7];
    const float* vlm_o_w    = (const float*)d_in[8];
    const float* vlm_gate_w = (const float*)d_in[9];
    const float* vlm_up_w   = (const float*)d_in[10];
    const float* vlm_down_w = (const float*)d_in[11];
    const float* exp_ln1_dw = (const float*)d_in[12];
    const float* exp_ln1_db = (const float*)d_in[13];
    const float* exp_ln2_dw = (const float*)d_in[14];
    const float* exp_ln2_db = (const float*)d_in[15];
    const float* exp_q_w    = (const float*)d_in[16];
    const float* exp_k_w    = (const float*)d_in[17];
    const float* exp_v_w    = (const float*)d_in[18];
    const float* exp_o_w    = (const float*)d_in[19];
    const float* exp_gate_w = (const float*)d_in[20];
    const float* exp_up_w   = (const float*)d_in[21];
    const float* exp_down_w = (const float*)d_in[22];
    const int*   position_ids = (const int*)d_in[23];

    float* OUTV = (float*)d_out;
    float* OUTE = OUTV + (long long)BATCH * S_V * W_V;

    // ---- workspace carve-up ----
    char* p = (char*)d_ws;
    auto alloc = [&](size_t bytes) {
        char* r = p; p += (bytes + 255) & ~(size_t)255; return r;
    };
    short* WT_VQ = (short*)alloc(2048ULL * 2048 * 2);
    short* WT_VK = (short*)alloc(256ULL  * 2048 * 2);
    short* WT_VV = (short*)alloc(256ULL  * 2048 * 2);
    short* WT_VO = (short*)alloc(2048ULL * 2048 * 2);
    short* WT_VG = (short*)alloc(16384ULL * 2048 * 2);
    short* WT_VU = (short*)alloc(16384ULL * 2048 * 2);
    short* WT_VD = (short*)alloc(2048ULL * 16384 * 2);
    short* WT_EQ = (short*)alloc(2048ULL * 1024 * 2);
    short* WT_EK = (short*)alloc(256ULL  * 1024 * 2);
    short* WT_EV = (short*)alloc(256ULL  * 1024 * 2);
    short* WT_EO = (short*)alloc(1024ULL * 2048 * 2);
    short* WT_EG = (short*)alloc(4096ULL * 1024 * 2);
    short* WT_EU = (short*)alloc(4096ULL * 1024 * 2);
    short* WT_ED = (short*)alloc(1024ULL * 4096 * 2);
    short* W0h = (short*)alloc(3072ULL * 2048 * 2);
    short* W1h = (short*)alloc(256ULL * 1024 * 2);
    float* MOD1 = (float*)alloc(4ULL * 3072 * 4);
    float* MOD2 = (float*)alloc(4ULL * 3072 * 4);
    float* Q  = (float*)alloc(4ULL * 832 * 2048 * 4);   // f32 Q (pre-rope)
    float* Kb = (float*)alloc(4ULL * 832 * 256 * 4);    // f32 K (pre-rope)
    short* QBq  = (short*)alloc(4ULL * 832 * 2048 * 2); // bf16 roped+scaled Q
    short* KB16 = (short*)alloc(4ULL * 832 * 256 * 2);  // bf16 roped K
    short* VB16 = (short*)alloc(4ULL * 832 * 256 * 2);  // bf16 V [B][S][D]
    short* VT   = (short*)alloc(4ULL * 256 * 832 * 2);  // bf16 V^T [B][D][S]
    short* QB = (short*)alloc(4ULL * 832 * 2048 * 2);   // attn out bf16
    size_t fixed = (size_t)(p - (char*)d_ws);
    int CR = 3072;
    if (fixed + 2ULL * 3072 * 16384 * 2 + 1024 > ws_size) CR = 768;
    short* G = (short*)alloc((size_t)CR * MLP_V * 2);
    short* U = (short*)alloc((size_t)CR * MLP_V * 2);

    const long long QBS = (long long)SEQ * 2048;
    const long long KBS = (long long)SEQ * 256;

    // ---- 1) weight transpose+convert ----
    tcvt_k<<<dim3(2048/64, 2048/64), 256, 0, stream>>>(vlm_q_w, WT_VQ, 2048, 2048);
    tcvt_k<<<dim3(256/64,  2048/64), 256, 0, stream>>>(vlm_k_w, WT_VK, 2048, 256);
    tcvt_k<<<dim3(256/64,  2048/64), 256, 0, stream>>>(vlm_v_w, WT_VV, 2048, 256);
    tcvt_k<<<dim3(2048/64, 2048/64), 256, 0, stream>>>(vlm_o_w, WT_VO, 2048, 2048);
    tcvt_k<<<dim3(16384/64,2048/64), 256, 0, stream>>>(vlm_gate_w, WT_VG, 2048, 16384);
    tcvt_k<<<dim3(16384/64,2048/64), 256, 0, stream>>>(vlm_up_w,   WT_VU, 2048, 16384);
    tcvt_k<<<dim3(2048/64,16384/64), 256, 0, stream>>>(vlm_down_w, WT_VD, 16384, 2048);
    tcvt_k<<<dim3(2048/64, 1024/64), 256, 0, stream>>>(exp_q_w, WT_EQ, 1024, 2048);
    tcvt_k<<<dim3(256/64,  1024/64), 256, 0, stream>>>(exp_k_w, WT_EK, 1024, 256);
    tcvt_k<<<dim3(256/64,  1024/64), 256, 0, stream>>>(exp_v_w, WT_EV, 1024, 256);
    tcvt_k<<<dim3(1024/64, 2048/64), 256, 0, stream>>>(exp_o_w, WT_EO, 2048, 1024);
    tcvt_k<<<dim3(4096/64, 1024/64), 256, 0, stream>>>(exp_gate_w, WT_EG, 1024, 4096);
    tcvt_k<<<dim3(4096/64, 1024/64), 256, 0, stream>>>(exp_up_w,   WT_EU, 1024, 4096);
    tcvt_k<<<dim3(1024/64, 4096/64), 256, 0, stream>>>(exp_down_w, WT_ED, 4096, 1024);

    // ---- 2) norms + modulation ----
    rms_scale_bf<<<BATCH * S_V, 256, 0, stream>>>(embeds_vlm, vlm_ln1_w, W0h, W_V);
    modln_k<<<dim3(12, BATCH), 256, 0, stream>>>(cond, exp_ln1_dw, exp_ln1_db, MOD1);
    modln_k<<<dim3(12, BATCH), 256, 0, stream>>>(cond, exp_ln2_dw, exp_ln2_db, MOD2);
    rms_mod_bf<<<BATCH * S_E, 256, 0, stream>>>(embeds_exp, MOD1, W1h, W_E, S_E);

    // ---- 3) q/k/v projections (V straight to bf16) ----
    bgemm_k<<<dim3(16, 24), 256, 0, stream>>>(W0h, WT_VQ, Q, nullptr, nullptr, nullptr, 0,
        2048, 2048, S_V, (long long)S_V * 2048, QBS, 0, 0);
    bgemm_k<<<dim3(2, 24), 256, 0, stream>>>(W0h, WT_VK, Kb, nullptr, nullptr, nullptr, 0,
        256, 2048, S_V, (long long)S_V * 2048, KBS, 0, 0);
    bgemm_k<<<dim3(2, 24), 256, 0, stream>>>(W0h, WT_VV, nullptr, VB16, nullptr, nullptr, 0,
        256, 2048, S_V, (long long)S_V * 2048, KBS, 0, 8);
    bgemm_k<<<dim3(16, 2), 256, 0, stream>>>(W1h, WT_EQ, Q + (long long)S_V * 2048,
        nullptr, nullptr, nullptr, 0, 2048, 1024, S_E, (long long)S_E * 1024, QBS, 0, 0);
    bgemm_k<<<dim3(2, 2), 256, 0, stream>>>(W1h, WT_EK, Kb + (long long)S_V * 256,
        nullptr, nullptr, nullptr, 0, 256, 1024, S_E, (long long)S_E * 1024, KBS, 0, 0);
    bgemm_k<<<dim3(2, 2), 256, 0, stream>>>(W1h, WT_EV, nullptr, VB16 + (long long)S_V * 256,
        nullptr, nullptr, 0, 256, 1024, S_E, (long long)S_E * 1024, KBS, 0, 8);

    // ---- 4) RoPE (f32->bf16) + V transpose + MFMA flash attention ----
    rope_bf_k<<<dim3(BATCH * SEQ, NH), 128, 0, stream>>>(
        Q, QBq, position_ids, NH, ATT_SCALE * LOG2E);
    rope_bf_k<<<dim3(BATCH * SEQ, 1), 128, 0, stream>>>(
        Kb, KB16, position_ids, 1, 1.0f);
    vt_k<<<dim3(13, 4, BATCH), 256, 0, stream>>>(VB16, VT);
    attn_mfma_k<<<dim3(13, NH, BATCH), 256, 0, stream>>>(QBq, KB16, VT, QB);

    // ---- 5) o-projections (+residual, expert gated) ----
    bgemm_k<<<dim3(16, 24), 256, 0, stream>>>(QB, WT_VO, OUTV, nullptr,
        embeds_vlm, nullptr, 0, 2048, 2048, S_V, QBS,
        (long long)S_V * 2048, (long long)S_V * 2048, 1);
    bgemm_k<<<dim3(8, 2), 256, 0, stream>>>(QB + (long long)S_V * 2048, WT_EO, OUTE,
        nullptr, embeds_exp, MOD1, 2048, 1024, 2048, S_E, QBS,
        (long long)S_E * 1024, (long long)S_E * 1024, 1 | 2);

    // ---- 6) second norms ----
    rms_scale_bf<<<BATCH * S_V, 256, 0, stream>>>(OUTV, vlm_ln2_w, W0h, W_V);
    rms_mod_bf<<<BATCH * S_E, 256, 0, stream>>>(OUTE, MOD2, W1h, W_E, S_E);

    // ---- 7) VLM MLP ----
    for (int c0 = 0; c0 < 3072; c0 += CR) {
        const short* Ac = W0h + (long long)c0 * 2048;
        long long g4 = (long long)CR * MLP_V / 4;
        bgemm_k<<<dim3(MLP_V / 128, CR / 128), 256, 0, stream>>>(Ac, WT_VG,
            nullptr, G, nullptr, nullptr, 0, MLP_V, 2048, CR,
            (long long)CR * 2048, (long long)CR * MLP_V, 0, 8);
        bgemm_k<<<dim3(MLP_V / 128, CR / 128), 256, 0, stream>>>(Ac, WT_VU,
            nullptr, U, nullptr, nullptr, 0, MLP_V, 2048, CR,
            (long long)CR * 2048, (long long)CR * MLP_V, 0, 8);
        gelu_mul_bf<<<(int)((g4 + 255) / 256), 256, 0, stream>>>(G, U, g4);
        bgemm_k<<<dim3(2048 / 128, CR / 128), 256, 0, stream>>>(G, WT_VD,
            OUTV + (long long)c0 * 2048, nullptr, nullptr, nullptr, 0,
            2048, MLP_V, CR, (long long)CR * MLP_V, (long long)CR * 2048, 0, 4);
    }

    // ---- 8) expert MLP (gated accumulate) ----
    bgemm_k<<<dim3(MLP_E / 128, 2), 256, 0, stream>>>(W1h, WT_EG,
        nullptr, G, nullptr, nullptr, 0, MLP_E, 1024, S_E,
        (long long)S_E * 1024, (long long)S_E * MLP_E, 0, 8);
    bgemm_k<<<dim3(MLP_E / 128, 2), 256, 0, stream>>>(W1h, WT_EU,
        nullptr, U, nullptr, nullptr, 0, MLP_E, 1024, S_E,
        (long long)S_E * 1024, (long long)S_E * MLP_E, 0, 8);
    long long e4 = (long long)256 * MLP_E / 4;
    gelu_mul_bf<<<(int)((e4 + 255) / 256), 256, 0, stream>>>(G, U, e4);
    bgemm_k<<<dim3(1024 / 128, 2), 256, 0, stream>>>(G, WT_ED, OUTE, nullptr,
        nullptr, MOD2, 2048, 1024, MLP_E, S_E,
        (long long)S_E * MLP_E, (long long)S_E * 1024, 0, 4 | 2);
}

// Round 3
// 2261.927 us; speedup vs baseline: 2.1109x; 1.1668x over previous
//
#include <hip/hip_runtime.h>
#include <math.h>

// ---------------------------------------------------------------------------
// Problem constants
// ---------------------------------------------------------------------------
#define BATCH 4
#define S_V 768
#define S_E 64
#define SEQ 832
#define W_V 2048
#define W_E 1024
#define NH 8
#define DH 256
#define MLP_V 16384
#define MLP_E 4096
#define EPS 1e-6f
#define ATT_SCALE 0.0625f
#define LOG2E 1.4426950408889634f

typedef __attribute__((ext_vector_type(8))) __bf16 bf16x8;
typedef __attribute__((ext_vector_type(4))) float f32x4;

__device__ __forceinline__ short f2bf(float f) {
    union { float f; unsigned u; } v; v.f = f;
    unsigned r = v.u + 0x7FFFu + ((v.u >> 16) & 1u);
    return (short)(r >> 16);
}
__device__ __forceinline__ float bf2f(short s) {
    union { unsigned u; float f; } v;
    v.u = ((unsigned)(unsigned short)s) << 16;
    return v.f;
}

// global -> LDS direct DMA, 16B per lane (m97 pattern).
#define G2L(gp, lp)                                                          \
    __builtin_amdgcn_global_load_lds(                                        \
        (const __attribute__((address_space(1))) unsigned int*)              \
            (unsigned long long)(const void*)(gp),                           \
        (__attribute__((address_space(3))) unsigned int*)                    \
            (unsigned int)(unsigned long long)(const void*)(lp),             \
        16, 0, 0)

// ---------------------------------------------------------------------------
// bf16 MFMA GEMM: 128x128 tile, BK=32, 4 waves, 16x16x32 MFMA.
// Ring-4 LDS buffers + counted vmcnt (T4). Steady state waits vmcnt(12)
// (3 tiles x 4 loads in flight); tail drains 8 -> 4 -> 0 (the round-2 bug:
// vmcnt(12) with <12 outstanding passes immediately, reading unlanded DMA).
// LDS reads XOR-swizzled (granule ^= row&3) with pre-swizzled G2L source
// (rule #21: linear dest + inverse-swizzled source + swizzled read).
// XCD-bijective block swizzle (T1/m204) for L2 locality.
//   flags: 1=+res, 2=*gate[b*3072+gate_off+n], 4=+=C (f32 accum), 8=write bf16
// Grid: (N/128, M/128), block 256.  K multiple of 32, K >= 128.
// ---------------------------------------------------------------------------
__global__ __launch_bounds__(256) void bgemm_k(
    const short* __restrict__ A, const short* __restrict__ Bt,
    float* __restrict__ C, short* __restrict__ Cb,
    const float* __restrict__ res, const float* __restrict__ gate, int gate_off,
    int N, int K, int rpb,
    long long a_bs, long long c_bs, long long r_bs, int flags)
{
    __shared__ short ring[4 * 8192];   // 4 bufs x (A[128][32] + B[128][32]) bf16

    const int t = threadIdx.x;

    // ---- XCD-bijective block swizzle (m204) ----
    const int gx = gridDim.x;
    const int nwg = gx * gridDim.y;
    const int orig = blockIdx.y * gx + blockIdx.x;
    const int qq = nwg >> 3, rr = nwg & 7;
    const int xcd = orig & 7, oi = orig >> 3;
    const int wg = (xcd < rr ? xcd * (qq + 1) : rr * (qq + 1) + (xcd - rr) * qq) + oi;
    const int bm = (wg / gx) * 128;
    const int bn = (wg % gx) * 128;

    // ---- staging setup: 4 x 16B per thread per tile (2 A-chunks, 2 B-chunks)
    const short* gsrc[4];
    int ldsb[4];   // byte offset within one ring buffer (16 KB)
#pragma unroll
    for (int l = 0; l < 4; l++) {
        int o   = (l & 1) * 4096 + t * 16;   // byte off within 8KB matrix tile
        int row = o >> 6;                    // 0..127 (64B rows)
        int g   = (o >> 4) & 3;              // 16B granule within row
        int kel = ((g ^ (row & 3)) << 3);    // swizzled k-element offset
        if (l < 2) {
            int m = bm + row;
            gsrc[l] = A + (long long)(m / rpb) * a_bs + (long long)(m % rpb) * K + kel;
            ldsb[l] = o;
        } else {
            gsrc[l] = Bt + (long long)(bn + row) * K + kel;
            ldsb[l] = 8192 + o;
        }
    }

    const int lane = t & 63;
    const int w    = t >> 6;
    const int wm   = (w >> 1) * 64;
    const int wn   = (w & 1) * 64;
    const int lr   = lane & 15;
    const int quad = lane >> 4;
    const int swq  = (quad ^ (lr & 3)) << 3;   // swizzled k-octet (elements)

    int aidx[4], bidx[4];
#pragma unroll
    for (int i = 0; i < 4; i++) aidx[i] = (wm + i * 16 + lr) * 32 + swq;
#pragma unroll
    for (int j = 0; j < 4; j++) bidx[j] = 4096 + (wn + j * 16 + lr) * 32 + swq;

    f32x4 acc[4][4];
#pragma unroll
    for (int i = 0; i < 4; i++)
#pragma unroll
        for (int j = 0; j < 4; j++) acc[i][j] = (f32x4){0.f, 0.f, 0.f, 0.f};

    const int NT = K >> 5;

    // ---- prologue: stage tiles 0..2 into ring bufs 0..2 ----
#pragma unroll
    for (int tt = 0; tt < 3; tt++) {
        if (tt < NT) {
#pragma unroll
            for (int l = 0; l < 4; l++) {
                G2L(gsrc[l], (char*)ring + tt * 16384 + ldsb[l]);
                gsrc[l] += 32;
            }
        }
    }

    // ---- main loop: 2 barriers/iter; counted vmcnt with tail drain ----
    for (int kt = 0; kt < NT; kt++) {
        if (kt + 3 < NT) {
            int b = (kt + 3) & 3;
#pragma unroll
            for (int l = 0; l < 4; l++) {
                G2L(gsrc[l], (char*)ring + b * 16384 + ldsb[l]);
                gsrc[l] += 32;
            }
            // 3 newer tiles (12 loads) in flight: tile kt has landed.
            asm volatile("s_waitcnt vmcnt(12)" ::: "memory");
        } else {
            int rem = NT - 1 - kt;   // tiles staged after the current one
            if (rem >= 2)      asm volatile("s_waitcnt vmcnt(8)" ::: "memory");
            else if (rem == 1) asm volatile("s_waitcnt vmcnt(4)" ::: "memory");
            else               asm volatile("s_waitcnt vmcnt(0)" ::: "memory");
        }
        asm volatile("s_barrier" ::: "memory");

        const short* sb = ring + (kt & 3) * 8192;
        bf16x8 af[4], bfr[4];
#pragma unroll
        for (int i = 0; i < 4; i++) af[i]  = *(const bf16x8*)&sb[aidx[i]];
#pragma unroll
        for (int j = 0; j < 4; j++) bfr[j] = *(const bf16x8*)&sb[bidx[j]];
#pragma unroll
        for (int i = 0; i < 4; i++)
#pragma unroll
            for (int j = 0; j < 4; j++)
                acc[i][j] = __builtin_amdgcn_mfma_f32_16x16x32_bf16(
                    af[i], bfr[j], acc[i][j], 0, 0, 0);
        // my LDS reads done -> barrier so next iteration's stage into this
        // ring slot cannot overwrite data another wave still reads.
        asm volatile("s_waitcnt lgkmcnt(0)" ::: "memory");
        asm volatile("s_barrier" ::: "memory");
    }

    // ---- epilogue: D row = quad*4+reg, col = lane&15 (m89-verified) ----
#pragma unroll
    for (int i = 0; i < 4; i++) {
#pragma unroll
        for (int r = 0; r < 4; r++) {
            int m = bm + wm + i * 16 + quad * 4 + r;
            long long bb = m / rpb;
            long long ss = m % rpb;
            long long rowb = bb * c_bs + ss * (long long)N;
            const float* rp = (flags & 1) ? res + bb * r_bs + ss * (long long)N : nullptr;
            const float* gp = (flags & 2) ? gate + bb * 3072 + gate_off : nullptr;
#pragma unroll
            for (int j = 0; j < 4; j++) {
                int n = bn + wn + j * 16 + lr;
                float v = acc[i][j][r];
                if (flags & 2) v *= gp[n];
                if (flags & 4) v += C[rowb + n];
                if (flags & 1) v += rp[n];
                if (flags & 8) Cb[rowb + n] = f2bf(v);
                else           C[rowb + n] = v;
            }
        }
    }
}

// ---------------------------------------------------------------------------
// Transpose + f32->bf16: W[K][N] f32  ->  Wt[N][K] bf16.  Grid (N/64, K/64).
// ---------------------------------------------------------------------------
__global__ __launch_bounds__(256) void tcvt_k(
    const float* __restrict__ W, short* __restrict__ Wt, int K, int N)
{
    __shared__ float tile[64][65];
    const int bx = blockIdx.x;   // N / 64
    const int by = blockIdx.y;   // K / 64
    const int t = threadIdx.x;
#pragma unroll
    for (int p = 0; p < 4; p++) {
        int idx = p * 256 + t;
        int r = idx >> 4;
        int c4 = (idx & 15) << 2;
        float4 v = *(const float4*)&W[(long long)(by * 64 + r) * N + bx * 64 + c4];
        tile[r][c4] = v.x; tile[r][c4 + 1] = v.y;
        tile[r][c4 + 2] = v.z; tile[r][c4 + 3] = v.w;
    }
    __syncthreads();
#pragma unroll
    for (int p = 0; p < 8; p++) {
        int idx = p * 256 + t;
        int n  = idx >> 5;
        int kp = idx & 31;
        unsigned lo = (unsigned)(unsigned short)f2bf(tile[kp * 2][n]);
        unsigned hi = (unsigned)(unsigned short)f2bf(tile[kp * 2 + 1][n]);
        *(unsigned*)&Wt[(long long)(bx * 64 + n) * K + by * 64 + kp * 2] =
            lo | (hi << 16);
    }
}

// ---------------------------------------------------------------------------
// RMSNorm * (1+w) -> bf16
// ---------------------------------------------------------------------------
__global__ __launch_bounds__(256) void rms_scale_bf(
    const float* __restrict__ x, const float* __restrict__ w,
    short* __restrict__ out, int C)
{
    const int row = blockIdx.x;
    const int t = threadIdx.x;
    const float* xp = x + (long long)row * C;
    short* op = out + (long long)row * C;
    float ss = 0.f;
    for (int i = t; i < C; i += 256) { float v = xp[i]; ss += v * v; }
    __shared__ float sred[256];
    sred[t] = ss;
    __syncthreads();
    for (int off = 128; off > 0; off >>= 1) {
        if (t < off) sred[t] += sred[t + off];
        __syncthreads();
    }
    float scale = rsqrtf(sred[0] / (float)C + EPS);
    for (int i = t; i < C; i += 256) op[i] = f2bf(xp[i] * scale * (1.f + w[i]));
}

// adaLN RMSNorm -> bf16 : rms(x)*(1+mod[b,i]) + mod[b,C+i]
__global__ __launch_bounds__(256) void rms_mod_bf(
    const float* __restrict__ x, const float* __restrict__ mod,
    short* __restrict__ out, int C, int rows_per_b)
{
    const int row = blockIdx.x;
    const int t = threadIdx.x;
    const int b = row / rows_per_b;
    const float* xp = x + (long long)row * C;
    const float* mp = mod + (long long)b * 3072;
    short* op = out + (long long)row * C;
    float ss = 0.f;
    for (int i = t; i < C; i += 256) { float v = xp[i]; ss += v * v; }
    __shared__ float sred[256];
    sred[t] = ss;
    __syncthreads();
    for (int off = 128; off > 0; off >>= 1) {
        if (t < off) sred[t] += sred[t + off];
        __syncthreads();
    }
    float scale = rsqrtf(sred[0] / (float)C + EPS);
    for (int i = t; i < C; i += 256)
        op[i] = f2bf(xp[i] * scale * (1.f + mp[i]) + mp[C + i]);
}

// ---------------------------------------------------------------------------
// Modulation: mod[b,n] = cond[b,:] @ dw[:,n] + db[n]
// ---------------------------------------------------------------------------
__global__ __launch_bounds__(256) void modln_k(
    const float* __restrict__ cond, const float* __restrict__ dw,
    const float* __restrict__ db, float* __restrict__ out)
{
    const int b = blockIdx.y;
    const int n = blockIdx.x * 256 + threadIdx.x;
    __shared__ float cs[1024];
    for (int i = threadIdx.x; i < 1024; i += 256) cs[i] = cond[b * 1024 + i];
    __syncthreads();
    float acc = db[n];
    for (int k = 0; k < 1024; k++) acc += cs[k] * dw[(long long)k * 3072 + n];
    out[b * 3072 + n] = acc;
}

// ---------------------------------------------------------------------------
// RoPE f32 -> bf16 (scaled). x[B*SEQ, heads, DH] f32; out same layout bf16.
// ---------------------------------------------------------------------------
__global__ __launch_bounds__(128) void rope_bf_k(
    const float* __restrict__ x, short* __restrict__ out,
    const int* __restrict__ pos_ids, int heads, float scale)
{
    const int bs = blockIdx.x;
    const int h = blockIdx.y;
    const int d = threadIdx.x;
    const float p = (float)pos_ids[bs];
    const float inv = powf(10000.f, -(float)d / 128.f);
    const float fr = p * inv;
    const float c = cosf(fr), sn = sinf(fr);
    const float* xp = x + ((long long)bs * heads + h) * DH;
    short* op = out + ((long long)bs * heads + h) * DH;
    float x1 = xp[d];
    float x2 = xp[d + 128];
    op[d]       = f2bf((x1 * c - x2 * sn) * scale);
    op[d + 128] = f2bf((x2 * c + x1 * sn) * scale);
}

// ---------------------------------------------------------------------------
// V transpose: V[B][SEQ][DH] bf16 -> Vt[B][DH][SEQ] bf16. Grid (13, 4, B).
// ---------------------------------------------------------------------------
__global__ __launch_bounds__(256) void vt_k(
    const short* __restrict__ V, short* __restrict__ Vt)
{
    __shared__ short tile[64][72];
    const int s0 = blockIdx.x * 64;
    const int d0 = blockIdx.y * 64;
    const int b  = blockIdx.z;
    const int t = threadIdx.x;
#pragma unroll
    for (int i = 0; i < 2; i++) {
        int lin = i * 256 + t;          // 0..511
        int r = lin >> 3;               // s row 0..63
        int c8 = (lin & 7) * 8;         // d col 0..56
        *(uint4*)&tile[r][c8] =
            *(const uint4*)&V[((long long)(b * SEQ + s0 + r) << 8) + d0 + c8];
    }
    __syncthreads();
#pragma unroll
    for (int i = 0; i < 8; i++) {
        int lin = i * 256 + t;          // 0..2047
        int dr = lin >> 5;              // d row 0..63
        int sp = (lin & 31) * 2;        // s pair
        unsigned lo = (unsigned)(unsigned short)tile[sp][dr];
        unsigned hi = (unsigned)(unsigned short)tile[sp + 1][dr];
        *(unsigned*)&Vt[(long long)(b * 256 + d0 + dr) * SEQ + s0 + sp] =
            lo | (hi << 16);
    }
}

// ---------------------------------------------------------------------------
// MFMA flash attention (verified in round 1).
// ---------------------------------------------------------------------------
__global__ __launch_bounds__(256) void attn_mfma_k(
    const short* __restrict__ Qb, const short* __restrict__ Kb,
    const short* __restrict__ Vt, short* __restrict__ out)
{
    __shared__ short Pl[4][16][72];   // per-wave P tile [row][key], padded
    const int bx = blockIdx.x;
    const int h  = blockIdx.y;
    const int b  = blockIdx.z;
    const int t  = threadIdx.x;
    const int w    = t >> 6;
    const int lane = t & 63;
    const int lr   = lane & 15;
    const int q4   = lane >> 4;

    const int r0 = bx * 64 + w * 16;           // wave's global row base
    const int nt = (bx == 12) ? 13 : 12;       // k-tiles of 64 keys

    bf16x8 qf[8];
    const short* qrow = Qb + (((long long)(b * SEQ + r0 + lr) * NH + h) << 8) + q4 * 8;
#pragma unroll
    for (int ks = 0; ks < 8; ks++)
        qf[ks] = *(const bf16x8*)(qrow + ks * 32);

    f32x4 acc_o[16];
#pragma unroll
    for (int n = 0; n < 16; n++) acc_o[n] = (f32x4){0.f, 0.f, 0.f, 0.f};
    float m_run[4], l_run[4];
#pragma unroll
    for (int r = 0; r < 4; r++) { m_run[r] = -1e30f; l_run[r] = 0.f; }

    for (int kt = 0; kt < nt; kt++) {
        const int k0 = kt * 64;
        f32x4 s[4];
#pragma unroll
        for (int n = 0; n < 4; n++) {
            s[n] = (f32x4){0.f, 0.f, 0.f, 0.f};
            const short* krow =
                Kb + ((long long)(b * SEQ + k0 + n * 16 + lr) << 8) + q4 * 8;
#pragma unroll
            for (int ks = 0; ks < 8; ks++) {
                bf16x8 kf = *(const bf16x8*)(krow + ks * 32);
                s[n] = __builtin_amdgcn_mfma_f32_16x16x32_bf16(qf[ks], kf, s[n], 0, 0, 0);
            }
        }
        if (bx == 12 && kt == 12) {
#pragma unroll
            for (int n = 0; n < 4; n++) {
                int kg = k0 + n * 16 + lr;
#pragma unroll
                for (int r = 0; r < 4; r++) {
                    int rg = r0 + q4 * 4 + r;
                    if (kg > rg) s[n][r] = -1e30f;
                }
            }
        }
        float mt[4];
#pragma unroll
        for (int r = 0; r < 4; r++)
            mt[r] = fmaxf(fmaxf(s[0][r], s[1][r]), fmaxf(s[2][r], s[3][r]));
#pragma unroll
        for (int off = 8; off >= 1; off >>= 1)
#pragma unroll
            for (int r = 0; r < 4; r++)
                mt[r] = fmaxf(mt[r], __shfl_xor(mt[r], off));
        bool grow = (mt[0] > m_run[0]) | (mt[1] > m_run[1]) |
                    (mt[2] > m_run[2]) | (mt[3] > m_run[3]);
        if (__ballot(grow)) {
            float sf[4];
#pragma unroll
            for (int r = 0; r < 4; r++) {
                float mn = fmaxf(m_run[r], mt[r]);
                sf[r] = exp2f(m_run[r] - mn);
                m_run[r] = mn;
                l_run[r] *= sf[r];
            }
#pragma unroll
            for (int n = 0; n < 16; n++)
#pragma unroll
                for (int r = 0; r < 4; r++) acc_o[n][r] *= sf[r];
        }
        float ts[4] = {0.f, 0.f, 0.f, 0.f};
#pragma unroll
        for (int n = 0; n < 4; n++) {
#pragma unroll
            for (int r = 0; r < 4; r++) {
                float p = exp2f(s[n][r] - m_run[r]);
                ts[r] += p;
                Pl[w][q4 * 4 + r][n * 16 + lr] = f2bf(p);
            }
        }
#pragma unroll
        for (int off = 8; off >= 1; off >>= 1)
#pragma unroll
            for (int r = 0; r < 4; r++) ts[r] += __shfl_xor(ts[r], off);
#pragma unroll
        for (int r = 0; r < 4; r++) l_run[r] += ts[r];
        bf16x8 pa[2];
#pragma unroll
        for (int ss2 = 0; ss2 < 2; ss2++)
            pa[ss2] = *(const bf16x8*)&Pl[w][lr][ss2 * 32 + q4 * 8];
        const short* vbase = Vt + ((long long)b * 256 + lr) * SEQ + k0 + q4 * 8;
#pragma unroll
        for (int n = 0; n < 16; n++) {
            const short* vrow = vbase + (long long)n * 16 * SEQ;
            bf16x8 vf0 = *(const bf16x8*)(vrow);
            bf16x8 vf1 = *(const bf16x8*)(vrow + 32);
            acc_o[n] = __builtin_amdgcn_mfma_f32_16x16x32_bf16(pa[0], vf0, acc_o[n], 0, 0, 0);
            acc_o[n] = __builtin_amdgcn_mfma_f32_16x16x32_bf16(pa[1], vf1, acc_o[n], 0, 0, 0);
        }
    }
    float rinv[4];
#pragma unroll
    for (int r = 0; r < 4; r++) rinv[r] = 1.f / l_run[r];
#pragma unroll
    for (int n = 0; n < 16; n++) {
#pragma unroll
        for (int r = 0; r < 4; r++) {
            int srow = r0 + q4 * 4 + r;
            out[(((long long)(b * SEQ + srow) * NH + h) << 8) + n * 16 + lr] =
                f2bf(acc_o[n][r] * rinv[r]);
        }
    }
}

// ---------------------------------------------------------------------------
// g = gelu_tanh(g) * u  (bf16, 4 elements per thread)
// ---------------------------------------------------------------------------
__global__ __launch_bounds__(256) void gelu_mul_bf(
    short* __restrict__ g, const short* __restrict__ u, long long n4)
{
    long long i = (long long)blockIdx.x * 256 + threadIdx.x;
    if (i >= n4) return;
    uint2 gv = ((const uint2*)g)[i];
    uint2 uv = ((const uint2*)u)[i];
    unsigned w[2] = {gv.x, gv.y};
    unsigned ww[2] = {uv.x, uv.y};
    unsigned o[2];
#pragma unroll
    for (int p = 0; p < 2; p++) {
        unsigned res = 0;
#pragma unroll
        for (int h = 0; h < 2; h++) {
            float x = bf2f((short)((w[p] >> (16 * h)) & 0xFFFF));
            float uu = bf2f((short)((ww[p] >> (16 * h)) & 0xFFFF));
            float th = tanhf(0.7978845608028654f * (x + 0.044715f * x * x * x));
            float r = 0.5f * x * (1.f + th) * uu;
            res |= ((unsigned)(unsigned short)f2bf(r)) << (16 * h);
        }
        o[p] = res;
    }
    ((uint2*)g)[i] = make_uint2(o[0], o[1]);
}

// ---------------------------------------------------------------------------
// kernel_launch
// ---------------------------------------------------------------------------
extern "C" void kernel_launch(void* const* d_in, const int* in_sizes, int n_in,
                              void* d_out, int out_size, void* d_ws, size_t ws_size,
                              hipStream_t stream)
{
    const float* embeds_vlm = (const float*)d_in[0];
    const float* embeds_exp = (const float*)d_in[1];
    const float* cond       = (const float*)d_in[2];
    const float* vlm_ln1_w  = (const float*)d_in[3];
    const float* vlm_ln2_w  = (const float*)d_in[4];
    const float* vlm_q_w    = (const float*)d_in[5];
    const float* vlm_k_w    = (const float*)d_in[6];
    const float* vlm_v_w    = (const float*)d_in[7];
    const float* vlm_o_w    = (const float*)d_in[8];
    const float* vlm_gate_w = (const float*)d_in[9];
    const float* vlm_up_w   = (const float*)d_in[10];
    const float* vlm_down_w = (const float*)d_in[11];
    const float* exp_ln1_dw = (const float*)d_in[12];
    const float* exp_ln1_db = (const float*)d_in[13];
    const float* exp_ln2_dw = (const float*)d_in[14];
    const float* exp_ln2_db = (const float*)d_in[15];
    const float* exp_q_w    = (const float*)d_in[16];
    const float* exp_k_w    = (const float*)d_in[17];
    const float* exp_v_w    = (const float*)d_in[18];
    const float* exp_o_w    = (const float*)d_in[19];
    const float* exp_gate_w = (const float*)d_in[20];
    const float* exp_up_w   = (const float*)d_in[21];
    const float* exp_down_w = (const float*)d_in[22];
    const int*   position_ids = (const int*)d_in[23];

    float* OUTV = (float*)d_out;
    float* OUTE = OUTV + (long long)BATCH * S_V * W_V;

    // ---- workspace carve-up ----
    char* p = (char*)d_ws;
    auto alloc = [&](size_t bytes) {
        char* r = p; p += (bytes + 255) & ~(size_t)255; return r;
    };
    short* WT_VQ = (short*)alloc(2048ULL * 2048 * 2);
    short* WT_VK = (short*)alloc(256ULL  * 2048 * 2);
    short* WT_VV = (short*)alloc(256ULL  * 2048 * 2);
    short* WT_VO = (short*)alloc(2048ULL * 2048 * 2);
    short* WT_VG = (short*)alloc(16384ULL * 2048 * 2);
    short* WT_VU = (short*)alloc(16384ULL * 2048 * 2);
    short* WT_VD = (short*)alloc(2048ULL * 16384 * 2);
    short* WT_EQ = (short*)alloc(2048ULL * 1024 * 2);
    short* WT_EK = (short*)alloc(256ULL  * 1024 * 2);
    short* WT_EV = (short*)alloc(256ULL  * 1024 * 2);
    short* WT_EO = (short*)alloc(1024ULL * 2048 * 2);
    short* WT_EG = (short*)alloc(4096ULL * 1024 * 2);
    short* WT_EU = (short*)alloc(4096ULL * 1024 * 2);
    short* WT_ED = (short*)alloc(1024ULL * 4096 * 2);
    short* W0h = (short*)alloc(3072ULL * 2048 * 2);
    short* W1h = (short*)alloc(256ULL * 1024 * 2);
    float* MOD1 = (float*)alloc(4ULL * 3072 * 4);
    float* MOD2 = (float*)alloc(4ULL * 3072 * 4);
    float* Q  = (float*)alloc(4ULL * 832 * 2048 * 4);   // f32 Q (pre-rope)
    float* Kb = (float*)alloc(4ULL * 832 * 256 * 4);    // f32 K (pre-rope)
    short* QBq  = (short*)alloc(4ULL * 832 * 2048 * 2); // bf16 roped+scaled Q
    short* KB16 = (short*)alloc(4ULL * 832 * 256 * 2);  // bf16 roped K
    short* VB16 = (short*)alloc(4ULL * 832 * 256 * 2);  // bf16 V [B][S][D]
    short* VT   = (short*)alloc(4ULL * 256 * 832 * 2);  // bf16 V^T [B][D][S]
    short* QB = (short*)alloc(4ULL * 832 * 2048 * 2);   // attn out bf16
    size_t fixed = (size_t)(p - (char*)d_ws);
    int CR = 3072;
    if (fixed + 2ULL * 3072 * 16384 * 2 + 1024 > ws_size) CR = 768;
    short* G = (short*)alloc((size_t)CR * MLP_V * 2);
    short* U = (short*)alloc((size_t)CR * MLP_V * 2);

    const long long QBS = (long long)SEQ * 2048;
    const long long KBS = (long long)SEQ * 256;

    // ---- 1) weight transpose+convert ----
    tcvt_k<<<dim3(2048/64, 2048/64), 256, 0, stream>>>(vlm_q_w, WT_VQ, 2048, 2048);
    tcvt_k<<<dim3(256/64,  2048/64), 256, 0, stream>>>(vlm_k_w, WT_VK, 2048, 256);
    tcvt_k<<<dim3(256/64,  2048/64), 256, 0, stream>>>(vlm_v_w, WT_VV, 2048, 256);
    tcvt_k<<<dim3(2048/64, 2048/64), 256, 0, stream>>>(vlm_o_w, WT_VO, 2048, 2048);
    tcvt_k<<<dim3(16384/64,2048/64), 256, 0, stream>>>(vlm_gate_w, WT_VG, 2048, 16384);
    tcvt_k<<<dim3(16384/64,2048/64), 256, 0, stream>>>(vlm_up_w,   WT_VU, 2048, 16384);
    tcvt_k<<<dim3(2048/64,16384/64), 256, 0, stream>>>(vlm_down_w, WT_VD, 16384, 2048);
    tcvt_k<<<dim3(2048/64, 1024/64), 256, 0, stream>>>(exp_q_w, WT_EQ, 1024, 2048);
    tcvt_k<<<dim3(256/64,  1024/64), 256, 0, stream>>>(exp_k_w, WT_EK, 1024, 256);
    tcvt_k<<<dim3(256/64,  1024/64), 256, 0, stream>>>(exp_v_w, WT_EV, 1024, 256);
    tcvt_k<<<dim3(1024/64, 2048/64), 256, 0, stream>>>(exp_o_w, WT_EO, 2048, 1024);
    tcvt_k<<<dim3(4096/64, 1024/64), 256, 0, stream>>>(exp_gate_w, WT_EG, 1024, 4096);
    tcvt_k<<<dim3(4096/64, 1024/64), 256, 0, stream>>>(exp_up_w,   WT_EU, 1024, 4096);
    tcvt_k<<<dim3(1024/64, 4096/64), 256, 0, stream>>>(exp_down_w, WT_ED, 4096, 1024);

    // ---- 2) norms + modulation ----
    rms_scale_bf<<<BATCH * S_V, 256, 0, stream>>>(embeds_vlm, vlm_ln1_w, W0h, W_V);
    modln_k<<<dim3(12, BATCH), 256, 0, stream>>>(cond, exp_ln1_dw, exp_ln1_db, MOD1);
    modln_k<<<dim3(12, BATCH), 256, 0, stream>>>(cond, exp_ln2_dw, exp_ln2_db, MOD2);
    rms_mod_bf<<<BATCH * S_E, 256, 0, stream>>>(embeds_exp, MOD1, W1h, W_E, S_E);

    // ---- 3) q/k/v projections (V straight to bf16) ----
    bgemm_k<<<dim3(16, 24), 256, 0, stream>>>(W0h, WT_VQ, Q, nullptr, nullptr, nullptr, 0,
        2048, 2048, S_V, (long long)S_V * 2048, QBS, 0, 0);
    bgemm_k<<<dim3(2, 24), 256, 0, stream>>>(W0h, WT_VK, Kb, nullptr, nullptr, nullptr, 0,
        256, 2048, S_V, (long long)S_V * 2048, KBS, 0, 0);
    bgemm_k<<<dim3(2, 24), 256, 0, stream>>>(W0h, WT_VV, nullptr, VB16, nullptr, nullptr, 0,
        256, 2048, S_V, (long long)S_V * 2048, KBS, 0, 8);
    bgemm_k<<<dim3(16, 2), 256, 0, stream>>>(W1h, WT_EQ, Q + (long long)S_V * 2048,
        nullptr, nullptr, nullptr, 0, 2048, 1024, S_E, (long long)S_E * 1024, QBS, 0, 0);
    bgemm_k<<<dim3(2, 2), 256, 0, stream>>>(W1h, WT_EK, Kb + (long long)S_V * 256,
        nullptr, nullptr, nullptr, 0, 256, 1024, S_E, (long long)S_E * 1024, KBS, 0, 0);
    bgemm_k<<<dim3(2, 2), 256, 0, stream>>>(W1h, WT_EV, nullptr, VB16 + (long long)S_V * 256,
        nullptr, nullptr, 0, 256, 1024, S_E, (long long)S_E * 1024, KBS, 0, 8);

    // ---- 4) RoPE (f32->bf16) + V transpose + MFMA flash attention ----
    rope_bf_k<<<dim3(BATCH * SEQ, NH), 128, 0, stream>>>(
        Q, QBq, position_ids, NH, ATT_SCALE * LOG2E);
    rope_bf_k<<<dim3(BATCH * SEQ, 1), 128, 0, stream>>>(
        Kb, KB16, position_ids, 1, 1.0f);
    vt_k<<<dim3(13, 4, BATCH), 256, 0, stream>>>(VB16, VT);
    attn_mfma_k<<<dim3(13, NH, BATCH), 256, 0, stream>>>(QBq, KB16, VT, QB);

    // ---- 5) o-projections (+residual, expert gated) ----
    bgemm_k<<<dim3(16, 24), 256, 0, stream>>>(QB, WT_VO, OUTV, nullptr,
        embeds_vlm, nullptr, 0, 2048, 2048, S_V, QBS,
        (long long)S_V * 2048, (long long)S_V * 2048, 1);
    bgemm_k<<<dim3(8, 2), 256, 0, stream>>>(QB + (long long)S_V * 2048, WT_EO, OUTE,
        nullptr, embeds_exp, MOD1, 2048, 1024, 2048, S_E, QBS,
        (long long)S_E * 1024, (long long)S_E * 1024, 1 | 2);

    // ---- 6) second norms ----
    rms_scale_bf<<<BATCH * S_V, 256, 0, stream>>>(OUTV, vlm_ln2_w, W0h, W_V);
    rms_mod_bf<<<BATCH * S_E, 256, 0, stream>>>(OUTE, MOD2, W1h, W_E, S_E);

    // ---- 7) VLM MLP ----
    for (int c0 = 0; c0 < 3072; c0 += CR) {
        const short* Ac = W0h + (long long)c0 * 2048;
        long long g4 = (long long)CR * MLP_V / 4;
        bgemm_k<<<dim3(MLP_V / 128, CR / 128), 256, 0, stream>>>(Ac, WT_VG,
            nullptr, G, nullptr, nullptr, 0, MLP_V, 2048, CR,
            (long long)CR * 2048, (long long)CR * MLP_V, 0, 8);
        bgemm_k<<<dim3(MLP_V / 128, CR / 128), 256, 0, stream>>>(Ac, WT_VU,
            nullptr, U, nullptr, nullptr, 0, MLP_V, 2048, CR,
            (long long)CR * 2048, (long long)CR * MLP_V, 0, 8);
        gelu_mul_bf<<<(int)((g4 + 255) / 256), 256, 0, stream>>>(G, U, g4);
        bgemm_k<<<dim3(2048 / 128, CR / 128), 256, 0, stream>>>(G, WT_VD,
            OUTV + (long long)c0 * 2048, nullptr, nullptr, nullptr, 0,
            2048, MLP_V, CR, (long long)CR * MLP_V, (long long)CR * 2048, 0, 4);
    }

    // ---- 8) expert MLP (gated accumulate) ----
    bgemm_k<<<dim3(MLP_E / 128, 2), 256, 0, stream>>>(W1h, WT_EG,
        nullptr, G, nullptr, nullptr, 0, MLP_E, 1024, S_E,
        (long long)S_E * 1024, (long long)S_E * MLP_E, 0, 8);
    bgemm_k<<<dim3(MLP_E / 128, 2), 256, 0, stream>>>(W1h, WT_EU,
        nullptr, U, nullptr, nullptr, 0, MLP_E, 1024, S_E,
        (long long)S_E * 1024, (long long)S_E * MLP_E, 0, 8);
    long long e4 = (long long)256 * MLP_E / 4;
    gelu_mul_bf<<<(int)((e4 + 255) / 256), 256, 0, stream>>>(G, U, e4);
    bgemm_k<<<dim3(1024 / 128, 2), 256, 0, stream>>>(G, WT_ED, OUTE, nullptr,
        nullptr, MOD2, 2048, 1024, MLP_E, S_E,
        (long long)S_E * MLP_E, (long long)S_E * 1024, 0, 4 | 2);
}

// Round 4
// 2202.464 us; speedup vs baseline: 2.1679x; 1.0270x over previous
//
#include <hip/hip_runtime.h>
#include <math.h>

// ---------------------------------------------------------------------------
// Problem constants
// ---------------------------------------------------------------------------
#define BATCH 4
#define S_V 768
#define S_E 64
#define SEQ 832
#define W_V 2048
#define W_E 1024
#define NH 8
#define DH 256
#define MLP_V 16384
#define MLP_E 4096
#define EPS 1e-6f
#define ATT_SCALE 0.0625f
#define LOG2E 1.4426950408889634f

typedef __attribute__((ext_vector_type(8))) __bf16 bf16x8;
typedef __attribute__((ext_vector_type(4))) float f32x4;

__device__ __forceinline__ short f2bf(float f) {
    union { float f; unsigned u; } v; v.f = f;
    unsigned r = v.u + 0x7FFFu + ((v.u >> 16) & 1u);
    return (short)(r >> 16);
}
__device__ __forceinline__ float bf2f(short s) {
    union { unsigned u; float f; } v;
    v.u = ((unsigned)(unsigned short)s) << 16;
    return v.f;
}

// global -> LDS direct DMA, 16B per lane (m97 pattern).
#define G2L(gp, lp)                                                          \
    __builtin_amdgcn_global_load_lds(                                        \
        (const __attribute__((address_space(1))) unsigned int*)              \
            (unsigned long long)(const void*)(gp),                           \
        (__attribute__((address_space(3))) unsigned int*)                    \
            (unsigned int)(unsigned long long)(const void*)(lp),             \
        16, 0, 0)

// ---------------------------------------------------------------------------
// bf16 MFMA GEMM: 128x128 tile, BK=32, 4 waves, 16x16x32 MFMA.
// Ring-3 LDS (48 KB -> 3 blocks/CU) + counted vmcnt: stage tile kt+2 each
// iteration, steady-state wait vmcnt(8); tail drains 4 -> 0.
// LDS bank swizzle: granule ^= (row>>1)&3. With 64B rows the bank base is
// parity*16 + granule*4; using row bits [2:1] spreads a 16-lane read phase
// over all 8 slots x 2 lanes = 2-way = free. (round-3's row&3 collapsed.)
// Staged via pre-swizzled G2L *source*, linear LDS dest (rule #21).
// XCD-bijective block swizzle (T1/m204) for L2 locality.
//   flags: 1=+res, 2=*gate[b*3072+gate_off+n], 4=+=C (f32 accum), 8=write bf16
// Grid: (N/128, M/128), block 256.  K multiple of 32, K >= 96.
// ---------------------------------------------------------------------------
__global__ __launch_bounds__(256) void bgemm_k(
    const short* __restrict__ A, const short* __restrict__ Bt,
    float* __restrict__ C, short* __restrict__ Cb,
    const float* __restrict__ res, const float* __restrict__ gate, int gate_off,
    int N, int K, int rpb,
    long long a_bs, long long c_bs, long long r_bs, int flags)
{
    __shared__ short ring[3 * 8192];   // 3 bufs x (A[128][32] + B[128][32]) bf16

    const int t = threadIdx.x;

    // ---- XCD-bijective block swizzle (m204) ----
    const int gx = gridDim.x;
    const int nwg = gx * gridDim.y;
    const int orig = blockIdx.y * gx + blockIdx.x;
    const int qq = nwg >> 3, rr = nwg & 7;
    const int xcd = orig & 7, oi = orig >> 3;
    const int wg = (xcd < rr ? xcd * (qq + 1) : rr * (qq + 1) + (xcd - rr) * qq) + oi;
    const int bm = (wg / gx) * 128;
    const int bn = (wg % gx) * 128;

    // ---- staging setup: 4 x 16B per thread per tile (2 A-chunks, 2 B-chunks)
    const short* gsrc[4];
    int ldsb[4];   // byte offset within one ring buffer (16 KB)
#pragma unroll
    for (int l = 0; l < 4; l++) {
        int o   = (l & 1) * 4096 + t * 16;   // byte off within 8KB matrix tile
        int row = o >> 6;                    // 0..127 (64B rows)
        int g   = (o >> 4) & 3;              // 16B granule within row
        int kel = ((g ^ ((row >> 1) & 3)) << 3);  // swizzled k-element offset
        if (l < 2) {
            int m = bm + row;
            gsrc[l] = A + (long long)(m / rpb) * a_bs + (long long)(m % rpb) * K + kel;
            ldsb[l] = o;
        } else {
            gsrc[l] = Bt + (long long)(bn + row) * K + kel;
            ldsb[l] = 8192 + o;
        }
    }

    const int lane = t & 63;
    const int w    = t >> 6;
    const int wm   = (w >> 1) * 64;
    const int wn   = (w & 1) * 64;
    const int lr   = lane & 15;
    const int quad = lane >> 4;
    // fragment rows are wm + i*16 + lr with wm%64==0, so (row>>1)&3 == (lr>>1)&3
    const int swq  = ((quad ^ ((lr >> 1) & 3)) << 3);  // swizzled k-octet (elems)

    int aidx[4], bidx[4];
#pragma unroll
    for (int i = 0; i < 4; i++) aidx[i] = (wm + i * 16 + lr) * 32 + swq;
#pragma unroll
    for (int j = 0; j < 4; j++) bidx[j] = 4096 + (wn + j * 16 + lr) * 32 + swq;

    f32x4 acc[4][4];
#pragma unroll
    for (int i = 0; i < 4; i++)
#pragma unroll
        for (int j = 0; j < 4; j++) acc[i][j] = (f32x4){0.f, 0.f, 0.f, 0.f};

    const int NT = K >> 5;

    // ---- prologue: stage tiles 0..1 into ring bufs 0..1 ----
#pragma unroll
    for (int tt = 0; tt < 2; tt++) {
        if (tt < NT) {
#pragma unroll
            for (int l = 0; l < 4; l++) {
                G2L(gsrc[l], (char*)ring + tt * 16384 + ldsb[l]);
                gsrc[l] += 32;
            }
        }
    }

    // ---- main loop: 2 barriers/iter; counted vmcnt with tail drain ----
    for (int kt = 0; kt < NT; kt++) {
        if (kt + 2 < NT) {
            int b = (kt + 2) % 3;
#pragma unroll
            for (int l = 0; l < 4; l++) {
                G2L(gsrc[l], (char*)ring + b * 16384 + ldsb[l]);
                gsrc[l] += 32;
            }
            // 2 newer tiles (8 loads) in flight: tile kt has landed.
            asm volatile("s_waitcnt vmcnt(8)" ::: "memory");
        } else {
            int rem = NT - 1 - kt;   // tiles staged after the current one
            if (rem == 1) asm volatile("s_waitcnt vmcnt(4)" ::: "memory");
            else          asm volatile("s_waitcnt vmcnt(0)" ::: "memory");
        }
        asm volatile("s_barrier" ::: "memory");

        const short* sb = ring + (kt % 3) * 8192;
        bf16x8 af[4], bfr[4];
#pragma unroll
        for (int i = 0; i < 4; i++) af[i]  = *(const bf16x8*)&sb[aidx[i]];
#pragma unroll
        for (int j = 0; j < 4; j++) bfr[j] = *(const bf16x8*)&sb[bidx[j]];
#pragma unroll
        for (int i = 0; i < 4; i++)
#pragma unroll
            for (int j = 0; j < 4; j++)
                acc[i][j] = __builtin_amdgcn_mfma_f32_16x16x32_bf16(
                    af[i], bfr[j], acc[i][j], 0, 0, 0);
        // my LDS reads done -> barrier so next iteration's stage into this
        // ring slot cannot overwrite data another wave still reads.
        asm volatile("s_waitcnt lgkmcnt(0)" ::: "memory");
        asm volatile("s_barrier" ::: "memory");
    }

    // ---- epilogue: D row = quad*4+reg, col = lane&15 (m89-verified) ----
#pragma unroll
    for (int i = 0; i < 4; i++) {
#pragma unroll
        for (int r = 0; r < 4; r++) {
            int m = bm + wm + i * 16 + quad * 4 + r;
            long long bb = m / rpb;
            long long ss = m % rpb;
            long long rowb = bb * c_bs + ss * (long long)N;
            const float* rp = (flags & 1) ? res + bb * r_bs + ss * (long long)N : nullptr;
            const float* gp = (flags & 2) ? gate + bb * 3072 + gate_off : nullptr;
#pragma unroll
            for (int j = 0; j < 4; j++) {
                int n = bn + wn + j * 16 + lr;
                float v = acc[i][j][r];
                if (flags & 2) v *= gp[n];
                if (flags & 4) v += C[rowb + n];
                if (flags & 1) v += rp[n];
                if (flags & 8) Cb[rowb + n] = f2bf(v);
                else           C[rowb + n] = v;
            }
        }
    }
}

// ---------------------------------------------------------------------------
// Transpose + f32->bf16: W[K][N] f32  ->  Wt[N][K] bf16.  Grid (N/64, K/64).
// ---------------------------------------------------------------------------
__global__ __launch_bounds__(256) void tcvt_k(
    const float* __restrict__ W, short* __restrict__ Wt, int K, int N)
{
    __shared__ float tile[64][65];
    const int bx = blockIdx.x;   // N / 64
    const int by = blockIdx.y;   // K / 64
    const int t = threadIdx.x;
#pragma unroll
    for (int p = 0; p < 4; p++) {
        int idx = p * 256 + t;
        int r = idx >> 4;
        int c4 = (idx & 15) << 2;
        float4 v = *(const float4*)&W[(long long)(by * 64 + r) * N + bx * 64 + c4];
        tile[r][c4] = v.x; tile[r][c4 + 1] = v.y;
        tile[r][c4 + 2] = v.z; tile[r][c4 + 3] = v.w;
    }
    __syncthreads();
#pragma unroll
    for (int p = 0; p < 8; p++) {
        int idx = p * 256 + t;
        int n  = idx >> 5;
        int kp = idx & 31;
        unsigned lo = (unsigned)(unsigned short)f2bf(tile[kp * 2][n]);
        unsigned hi = (unsigned)(unsigned short)f2bf(tile[kp * 2 + 1][n]);
        *(unsigned*)&Wt[(long long)(bx * 64 + n) * K + by * 64 + kp * 2] =
            lo | (hi << 16);
    }
}

// ---------------------------------------------------------------------------
// RMSNorm * (1+w) -> bf16
// ---------------------------------------------------------------------------
__global__ __launch_bounds__(256) void rms_scale_bf(
    const float* __restrict__ x, const float* __restrict__ w,
    short* __restrict__ out, int C)
{
    const int row = blockIdx.x;
    const int t = threadIdx.x;
    const float* xp = x + (long long)row * C;
    short* op = out + (long long)row * C;
    float ss = 0.f;
    for (int i = t; i < C; i += 256) { float v = xp[i]; ss += v * v; }
    __shared__ float sred[256];
    sred[t] = ss;
    __syncthreads();
    for (int off = 128; off > 0; off >>= 1) {
        if (t < off) sred[t] += sred[t + off];
        __syncthreads();
    }
    float scale = rsqrtf(sred[0] / (float)C + EPS);
    for (int i = t; i < C; i += 256) op[i] = f2bf(xp[i] * scale * (1.f + w[i]));
}

// adaLN RMSNorm -> bf16 : rms(x)*(1+mod[b,i]) + mod[b,C+i]
__global__ __launch_bounds__(256) void rms_mod_bf(
    const float* __restrict__ x, const float* __restrict__ mod,
    short* __restrict__ out, int C, int rows_per_b)
{
    const int row = blockIdx.x;
    const int t = threadIdx.x;
    const int b = row / rows_per_b;
    const float* xp = x + (long long)row * C;
    const float* mp = mod + (long long)b * 3072;
    short* op = out + (long long)row * C;
    float ss = 0.f;
    for (int i = t; i < C; i += 256) { float v = xp[i]; ss += v * v; }
    __shared__ float sred[256];
    sred[t] = ss;
    __syncthreads();
    for (int off = 128; off > 0; off >>= 1) {
        if (t < off) sred[t] += sred[t + off];
        __syncthreads();
    }
    float scale = rsqrtf(sred[0] / (float)C + EPS);
    for (int i = t; i < C; i += 256)
        op[i] = f2bf(xp[i] * scale * (1.f + mp[i]) + mp[C + i]);
}

// ---------------------------------------------------------------------------
// Modulation: mod[b,n] = cond[b,:] @ dw[:,n] + db[n]
// ---------------------------------------------------------------------------
__global__ __launch_bounds__(256) void modln_k(
    const float* __restrict__ cond, const float* __restrict__ dw,
    const float* __restrict__ db, float* __restrict__ out)
{
    const int b = blockIdx.y;
    const int n = blockIdx.x * 256 + threadIdx.x;
    __shared__ float cs[1024];
    for (int i = threadIdx.x; i < 1024; i += 256) cs[i] = cond[b * 1024 + i];
    __syncthreads();
    float acc = db[n];
    for (int k = 0; k < 1024; k++) acc += cs[k] * dw[(long long)k * 3072 + n];
    out[b * 3072 + n] = acc;
}

// ---------------------------------------------------------------------------
// RoPE f32 -> bf16 (scaled). x[B*SEQ, heads, DH] f32; out same layout bf16.
// ---------------------------------------------------------------------------
__global__ __launch_bounds__(128) void rope_bf_k(
    const float* __restrict__ x, short* __restrict__ out,
    const int* __restrict__ pos_ids, int heads, float scale)
{
    const int bs = blockIdx.x;
    const int h = blockIdx.y;
    const int d = threadIdx.x;
    const float p = (float)pos_ids[bs];
    const float inv = powf(10000.f, -(float)d / 128.f);
    const float fr = p * inv;
    const float c = cosf(fr), sn = sinf(fr);
    const float* xp = x + ((long long)bs * heads + h) * DH;
    short* op = out + ((long long)bs * heads + h) * DH;
    float x1 = xp[d];
    float x2 = xp[d + 128];
    op[d]       = f2bf((x1 * c - x2 * sn) * scale);
    op[d + 128] = f2bf((x2 * c + x1 * sn) * scale);
}

// ---------------------------------------------------------------------------
// V transpose: V[B][SEQ][DH] bf16 -> Vt[B][DH][SEQ] bf16. Grid (13, 4, B).
// ---------------------------------------------------------------------------
__global__ __launch_bounds__(256) void vt_k(
    const short* __restrict__ V, short* __restrict__ Vt)
{
    __shared__ short tile[64][72];
    const int s0 = blockIdx.x * 64;
    const int d0 = blockIdx.y * 64;
    const int b  = blockIdx.z;
    const int t = threadIdx.x;
#pragma unroll
    for (int i = 0; i < 2; i++) {
        int lin = i * 256 + t;          // 0..511
        int r = lin >> 3;               // s row 0..63
        int c8 = (lin & 7) * 8;         // d col 0..56
        *(uint4*)&tile[r][c8] =
            *(const uint4*)&V[((long long)(b * SEQ + s0 + r) << 8) + d0 + c8];
    }
    __syncthreads();
#pragma unroll
    for (int i = 0; i < 8; i++) {
        int lin = i * 256 + t;          // 0..2047
        int dr = lin >> 5;              // d row 0..63
        int sp = (lin & 31) * 2;        // s pair
        unsigned lo = (unsigned)(unsigned short)tile[sp][dr];
        unsigned hi = (unsigned)(unsigned short)tile[sp + 1][dr];
        *(unsigned*)&Vt[(long long)(b * 256 + d0 + dr) * SEQ + s0 + sp] =
            lo | (hi << 16);
    }
}

// ---------------------------------------------------------------------------
// MFMA flash attention (verified in round 1).
// ---------------------------------------------------------------------------
__global__ __launch_bounds__(256) void attn_mfma_k(
    const short* __restrict__ Qb, const short* __restrict__ Kb,
    const short* __restrict__ Vt, short* __restrict__ out)
{
    __shared__ short Pl[4][16][72];   // per-wave P tile [row][key], padded
    const int bx = blockIdx.x;
    const int h  = blockIdx.y;
    const int b  = blockIdx.z;
    const int t  = threadIdx.x;
    const int w    = t >> 6;
    const int lane = t & 63;
    const int lr   = lane & 15;
    const int q4   = lane >> 4;

    const int r0 = bx * 64 + w * 16;           // wave's global row base
    const int nt = (bx == 12) ? 13 : 12;       // k-tiles of 64 keys

    bf16x8 qf[8];
    const short* qrow = Qb + (((long long)(b * SEQ + r0 + lr) * NH + h) << 8) + q4 * 8;
#pragma unroll
    for (int ks = 0; ks < 8; ks++)
        qf[ks] = *(const bf16x8*)(qrow + ks * 32);

    f32x4 acc_o[16];
#pragma unroll
    for (int n = 0; n < 16; n++) acc_o[n] = (f32x4){0.f, 0.f, 0.f, 0.f};
    float m_run[4], l_run[4];
#pragma unroll
    for (int r = 0; r < 4; r++) { m_run[r] = -1e30f; l_run[r] = 0.f; }

    for (int kt = 0; kt < nt; kt++) {
        const int k0 = kt * 64;
        f32x4 s[4];
#pragma unroll
        for (int n = 0; n < 4; n++) {
            s[n] = (f32x4){0.f, 0.f, 0.f, 0.f};
            const short* krow =
                Kb + ((long long)(b * SEQ + k0 + n * 16 + lr) << 8) + q4 * 8;
#pragma unroll
            for (int ks = 0; ks < 8; ks++) {
                bf16x8 kf = *(const bf16x8*)(krow + ks * 32);
                s[n] = __builtin_amdgcn_mfma_f32_16x16x32_bf16(qf[ks], kf, s[n], 0, 0, 0);
            }
        }
        if (bx == 12 && kt == 12) {
#pragma unroll
            for (int n = 0; n < 4; n++) {
                int kg = k0 + n * 16 + lr;
#pragma unroll
                for (int r = 0; r < 4; r++) {
                    int rg = r0 + q4 * 4 + r;
                    if (kg > rg) s[n][r] = -1e30f;
                }
            }
        }
        float mt[4];
#pragma unroll
        for (int r = 0; r < 4; r++)
            mt[r] = fmaxf(fmaxf(s[0][r], s[1][r]), fmaxf(s[2][r], s[3][r]));
#pragma unroll
        for (int off = 8; off >= 1; off >>= 1)
#pragma unroll
            for (int r = 0; r < 4; r++)
                mt[r] = fmaxf(mt[r], __shfl_xor(mt[r], off));
        bool grow = (mt[0] > m_run[0]) | (mt[1] > m_run[1]) |
                    (mt[2] > m_run[2]) | (mt[3] > m_run[3]);
        if (__ballot(grow)) {
            float sf[4];
#pragma unroll
            for (int r = 0; r < 4; r++) {
                float mn = fmaxf(m_run[r], mt[r]);
                sf[r] = exp2f(m_run[r] - mn);
                m_run[r] = mn;
                l_run[r] *= sf[r];
            }
#pragma unroll
            for (int n = 0; n < 16; n++)
#pragma unroll
                for (int r = 0; r < 4; r++) acc_o[n][r] *= sf[r];
        }
        float ts[4] = {0.f, 0.f, 0.f, 0.f};
#pragma unroll
        for (int n = 0; n < 4; n++) {
#pragma unroll
            for (int r = 0; r < 4; r++) {
                float p = exp2f(s[n][r] - m_run[r]);
                ts[r] += p;
                Pl[w][q4 * 4 + r][n * 16 + lr] = f2bf(p);
            }
        }
#pragma unroll
        for (int off = 8; off >= 1; off >>= 1)
#pragma unroll
            for (int r = 0; r < 4; r++) ts[r] += __shfl_xor(ts[r], off);
#pragma unroll
        for (int r = 0; r < 4; r++) l_run[r] += ts[r];
        bf16x8 pa[2];
#pragma unroll
        for (int ss2 = 0; ss2 < 2; ss2++)
            pa[ss2] = *(const bf16x8*)&Pl[w][lr][ss2 * 32 + q4 * 8];
        const short* vbase = Vt + ((long long)b * 256 + lr) * SEQ + k0 + q4 * 8;
#pragma unroll
        for (int n = 0; n < 16; n++) {
            const short* vrow = vbase + (long long)n * 16 * SEQ;
            bf16x8 vf0 = *(const bf16x8*)(vrow);
            bf16x8 vf1 = *(const bf16x8*)(vrow + 32);
            acc_o[n] = __builtin_amdgcn_mfma_f32_16x16x32_bf16(pa[0], vf0, acc_o[n], 0, 0, 0);
            acc_o[n] = __builtin_amdgcn_mfma_f32_16x16x32_bf16(pa[1], vf1, acc_o[n], 0, 0, 0);
        }
    }
    float rinv[4];
#pragma unroll
    for (int r = 0; r < 4; r++) rinv[r] = 1.f / l_run[r];
#pragma unroll
    for (int n = 0; n < 16; n++) {
#pragma unroll
        for (int r = 0; r < 4; r++) {
            int srow = r0 + q4 * 4 + r;
            out[(((long long)(b * SEQ + srow) * NH + h) << 8) + n * 16 + lr] =
                f2bf(acc_o[n][r] * rinv[r]);
        }
    }
}

// ---------------------------------------------------------------------------
// g = gelu_tanh(g) * u  (bf16, 4 elements per thread)
// ---------------------------------------------------------------------------
__global__ __launch_bounds__(256) void gelu_mul_bf(
    short* __restrict__ g, const short* __restrict__ u, long long n4)
{
    long long i = (long long)blockIdx.x * 256 + threadIdx.x;
    if (i >= n4) return;
    uint2 gv = ((const uint2*)g)[i];
    uint2 uv = ((const uint2*)u)[i];
    unsigned w[2] = {gv.x, gv.y};
    unsigned ww[2] = {uv.x, uv.y};
    unsigned o[2];
#pragma unroll
    for (int p = 0; p < 2; p++) {
        unsigned res = 0;
#pragma unroll
        for (int h = 0; h < 2; h++) {
            float x = bf2f((short)((w[p] >> (16 * h)) & 0xFFFF));
            float uu = bf2f((short)((ww[p] >> (16 * h)) & 0xFFFF));
            float th = tanhf(0.7978845608028654f * (x + 0.044715f * x * x * x));
            float r = 0.5f * x * (1.f + th) * uu;
            res |= ((unsigned)(unsigned short)f2bf(r)) << (16 * h);
        }
        o[p] = res;
    }
    ((uint2*)g)[i] = make_uint2(o[0], o[1]);
}

// ---------------------------------------------------------------------------
// kernel_launch
// ---------------------------------------------------------------------------
extern "C" void kernel_launch(void* const* d_in, const int* in_sizes, int n_in,
                              void* d_out, int out_size, void* d_ws, size_t ws_size,
                              hipStream_t stream)
{
    const float* embeds_vlm = (const float*)d_in[0];
    const float* embeds_exp = (const float*)d_in[1];
    const float* cond       = (const float*)d_in[2];
    const float* vlm_ln1_w  = (const float*)d_in[3];
    const float* vlm_ln2_w  = (const float*)d_in[4];
    const float* vlm_q_w    = (const float*)d_in[5];
    const float* vlm_k_w    = (const float*)d_in[6];
    const float* vlm_v_w    = (const float*)d_in[7];
    const float* vlm_o_w    = (const float*)d_in[8];
    const float* vlm_gate_w = (const float*)d_in[9];
    const float* vlm_up_w   = (const float*)d_in[10];
    const float* vlm_down_w = (const float*)d_in[11];
    const float* exp_ln1_dw = (const float*)d_in[12];
    const float* exp_ln1_db = (const float*)d_in[13];
    const float* exp_ln2_dw = (const float*)d_in[14];
    const float* exp_ln2_db = (const float*)d_in[15];
    const float* exp_q_w    = (const float*)d_in[16];
    const float* exp_k_w    = (const float*)d_in[17];
    const float* exp_v_w    = (const float*)d_in[18];
    const float* exp_o_w    = (const float*)d_in[19];
    const float* exp_gate_w = (const float*)d_in[20];
    const float* exp_up_w   = (const float*)d_in[21];
    const float* exp_down_w = (const float*)d_in[22];
    const int*   position_ids = (const int*)d_in[23];

    float* OUTV = (float*)d_out;
    float* OUTE = OUTV + (long long)BATCH * S_V * W_V;

    // ---- workspace carve-up ----
    char* p = (char*)d_ws;
    auto alloc = [&](size_t bytes) {
        char* r = p; p += (bytes + 255) & ~(size_t)255; return r;
    };
    short* WT_VQ = (short*)alloc(2048ULL * 2048 * 2);
    short* WT_VK = (short*)alloc(256ULL  * 2048 * 2);
    short* WT_VV = (short*)alloc(256ULL  * 2048 * 2);
    short* WT_VO = (short*)alloc(2048ULL * 2048 * 2);
    short* WT_VG = (short*)alloc(16384ULL * 2048 * 2);
    short* WT_VU = (short*)alloc(16384ULL * 2048 * 2);
    short* WT_VD = (short*)alloc(2048ULL * 16384 * 2);
    short* WT_EQ = (short*)alloc(2048ULL * 1024 * 2);
    short* WT_EK = (short*)alloc(256ULL  * 1024 * 2);
    short* WT_EV = (short*)alloc(256ULL  * 1024 * 2);
    short* WT_EO = (short*)alloc(1024ULL * 2048 * 2);
    short* WT_EG = (short*)alloc(4096ULL * 1024 * 2);
    short* WT_EU = (short*)alloc(4096ULL * 1024 * 2);
    short* WT_ED = (short*)alloc(1024ULL * 4096 * 2);
    short* W0h = (short*)alloc(3072ULL * 2048 * 2);
    short* W1h = (short*)alloc(256ULL * 1024 * 2);
    float* MOD1 = (float*)alloc(4ULL * 3072 * 4);
    float* MOD2 = (float*)alloc(4ULL * 3072 * 4);
    float* Q  = (float*)alloc(4ULL * 832 * 2048 * 4);   // f32 Q (pre-rope)
    float* Kb = (float*)alloc(4ULL * 832 * 256 * 4);    // f32 K (pre-rope)
    short* QBq  = (short*)alloc(4ULL * 832 * 2048 * 2); // bf16 roped+scaled Q
    short* KB16 = (short*)alloc(4ULL * 832 * 256 * 2);  // bf16 roped K
    short* VB16 = (short*)alloc(4ULL * 832 * 256 * 2);  // bf16 V [B][S][D]
    short* VT   = (short*)alloc(4ULL * 256 * 832 * 2);  // bf16 V^T [B][D][S]
    short* QB = (short*)alloc(4ULL * 832 * 2048 * 2);   // attn out bf16
    size_t fixed = (size_t)(p - (char*)d_ws);
    int CR = 3072;
    if (fixed + 2ULL * 3072 * 16384 * 2 + 1024 > ws_size) CR = 768;
    short* G = (short*)alloc((size_t)CR * MLP_V * 2);
    short* U = (short*)alloc((size_t)CR * MLP_V * 2);

    const long long QBS = (long long)SEQ * 2048;
    const long long KBS = (long long)SEQ * 256;

    // ---- 1) weight transpose+convert ----
    tcvt_k<<<dim3(2048/64, 2048/64), 256, 0, stream>>>(vlm_q_w, WT_VQ, 2048, 2048);
    tcvt_k<<<dim3(256/64,  2048/64), 256, 0, stream>>>(vlm_k_w, WT_VK, 2048, 256);
    tcvt_k<<<dim3(256/64,  2048/64), 256, 0, stream>>>(vlm_v_w, WT_VV, 2048, 256);
    tcvt_k<<<dim3(2048/64, 2048/64), 256, 0, stream>>>(vlm_o_w, WT_VO, 2048, 2048);
    tcvt_k<<<dim3(16384/64,2048/64), 256, 0, stream>>>(vlm_gate_w, WT_VG, 2048, 16384);
    tcvt_k<<<dim3(16384/64,2048/64), 256, 0, stream>>>(vlm_up_w,   WT_VU, 2048, 16384);
    tcvt_k<<<dim3(2048/64,16384/64), 256, 0, stream>>>(vlm_down_w, WT_VD, 16384, 2048);
    tcvt_k<<<dim3(2048/64, 1024/64), 256, 0, stream>>>(exp_q_w, WT_EQ, 1024, 2048);
    tcvt_k<<<dim3(256/64,  1024/64), 256, 0, stream>>>(exp_k_w, WT_EK, 1024, 256);
    tcvt_k<<<dim3(256/64,  1024/64), 256, 0, stream>>>(exp_v_w, WT_EV, 1024, 256);
    tcvt_k<<<dim3(1024/64, 2048/64), 256, 0, stream>>>(exp_o_w, WT_EO, 2048, 1024);
    tcvt_k<<<dim3(4096/64, 1024/64), 256, 0, stream>>>(exp_gate_w, WT_EG, 1024, 4096);
    tcvt_k<<<dim3(4096/64, 1024/64), 256, 0, stream>>>(exp_up_w,   WT_EU, 1024, 4096);
    tcvt_k<<<dim3(1024/64, 4096/64), 256, 0, stream>>>(exp_down_w, WT_ED, 4096, 1024);

    // ---- 2) norms + modulation ----
    rms_scale_bf<<<BATCH * S_V, 256, 0, stream>>>(embeds_vlm, vlm_ln1_w, W0h, W_V);
    modln_k<<<dim3(12, BATCH), 256, 0, stream>>>(cond, exp_ln1_dw, exp_ln1_db, MOD1);
    modln_k<<<dim3(12, BATCH), 256, 0, stream>>>(cond, exp_ln2_dw, exp_ln2_db, MOD2);
    rms_mod_bf<<<BATCH * S_E, 256, 0, stream>>>(embeds_exp, MOD1, W1h, W_E, S_E);

    // ---- 3) q/k/v projections (V straight to bf16) ----
    bgemm_k<<<dim3(16, 24), 256, 0, stream>>>(W0h, WT_VQ, Q, nullptr, nullptr, nullptr, 0,
        2048, 2048, S_V, (long long)S_V * 2048, QBS, 0, 0);
    bgemm_k<<<dim3(2, 24), 256, 0, stream>>>(W0h, WT_VK, Kb, nullptr, nullptr, nullptr, 0,
        256, 2048, S_V, (long long)S_V * 2048, KBS, 0, 0);
    bgemm_k<<<dim3(2, 24), 256, 0, stream>>>(W0h, WT_VV, nullptr, VB16, nullptr, nullptr, 0,
        256, 2048, S_V, (long long)S_V * 2048, KBS, 0, 8);
    bgemm_k<<<dim3(16, 2), 256, 0, stream>>>(W1h, WT_EQ, Q + (long long)S_V * 2048,
        nullptr, nullptr, nullptr, 0, 2048, 1024, S_E, (long long)S_E * 1024, QBS, 0, 0);
    bgemm_k<<<dim3(2, 2), 256, 0, stream>>>(W1h, WT_EK, Kb + (long long)S_V * 256,
        nullptr, nullptr, nullptr, 0, 256, 1024, S_E, (long long)S_E * 1024, KBS, 0, 0);
    bgemm_k<<<dim3(2, 2), 256, 0, stream>>>(W1h, WT_EV, nullptr, VB16 + (long long)S_V * 256,
        nullptr, nullptr, 0, 256, 1024, S_E, (long long)S_E * 1024, KBS, 0, 8);

    // ---- 4) RoPE (f32->bf16) + V transpose + MFMA flash attention ----
    rope_bf_k<<<dim3(BATCH * SEQ, NH), 128, 0, stream>>>(
        Q, QBq, position_ids, NH, ATT_SCALE * LOG2E);
    rope_bf_k<<<dim3(BATCH * SEQ, 1), 128, 0, stream>>>(
        Kb, KB16, position_ids, 1, 1.0f);
    vt_k<<<dim3(13, 4, BATCH), 256, 0, stream>>>(VB16, VT);
    attn_mfma_k<<<dim3(13, NH, BATCH), 256, 0, stream>>>(QBq, KB16, VT, QB);

    // ---- 5) o-projections (+residual, expert gated) ----
    bgemm_k<<<dim3(16, 24), 256, 0, stream>>>(QB, WT_VO, OUTV, nullptr,
        embeds_vlm, nullptr, 0, 2048, 2048, S_V, QBS,
        (long long)S_V * 2048, (long long)S_V * 2048, 1);
    bgemm_k<<<dim3(8, 2), 256, 0, stream>>>(QB + (long long)S_V * 2048, WT_EO, OUTE,
        nullptr, embeds_exp, MOD1, 2048, 1024, 2048, S_E, QBS,
        (long long)S_E * 1024, (long long)S_E * 1024, 1 | 2);

    // ---- 6) second norms ----
    rms_scale_bf<<<BATCH * S_V, 256, 0, stream>>>(OUTV, vlm_ln2_w, W0h, W_V);
    rms_mod_bf<<<BATCH * S_E, 256, 0, stream>>>(OUTE, MOD2, W1h, W_E, S_E);

    // ---- 7) VLM MLP ----
    for (int c0 = 0; c0 < 3072; c0 += CR) {
        const short* Ac = W0h + (long long)c0 * 2048;
        long long g4 = (long long)CR * MLP_V / 4;
        bgemm_k<<<dim3(MLP_V / 128, CR / 128), 256, 0, stream>>>(Ac, WT_VG,
            nullptr, G, nullptr, nullptr, 0, MLP_V, 2048, CR,
            (long long)CR * 2048, (long long)CR * MLP_V, 0, 8);
        bgemm_k<<<dim3(MLP_V / 128, CR / 128), 256, 0, stream>>>(Ac, WT_VU,
            nullptr, U, nullptr, nullptr, 0, MLP_V, 2048, CR,
            (long long)CR * 2048, (long long)CR * MLP_V, 0, 8);
        gelu_mul_bf<<<(int)((g4 + 255) / 256), 256, 0, stream>>>(G, U, g4);
        bgemm_k<<<dim3(2048 / 128, CR / 128), 256, 0, stream>>>(G, WT_VD,
            OUTV + (long long)c0 * 2048, nullptr, nullptr, nullptr, 0,
            2048, MLP_V, CR, (long long)CR * MLP_V, (long long)CR * 2048, 0, 4);
    }

    // ---- 8) expert MLP (gated accumulate) ----
    bgemm_k<<<dim3(MLP_E / 128, 2), 256, 0, stream>>>(W1h, WT_EG,
        nullptr, G, nullptr, nullptr, 0, MLP_E, 1024, S_E,
        (long long)S_E * 1024, (long long)S_E * MLP_E, 0, 8);
    bgemm_k<<<dim3(MLP_E / 128, 2), 256, 0, stream>>>(W1h, WT_EU,
        nullptr, U, nullptr, nullptr, 0, MLP_E, 1024, S_E,
        (long long)S_E * 1024, (long long)S_E * MLP_E, 0, 8);
    long long e4 = (long long)256 * MLP_E / 4;
    gelu_mul_bf<<<(int)((e4 + 255) / 256), 256, 0, stream>>>(G, U, e4);
    bgemm_k<<<dim3(1024 / 128, 2), 256, 0, stream>>>(G, WT_ED, OUTE, nullptr,
        nullptr, MOD2, 2048, 1024, MLP_E, S_E,
        (long long)S_E * MLP_E, (long long)S_E * 1024, 0, 4 | 2);
}